// Round 7
// baseline (516.452 us; speedup 1.0000x reference)
//
#include <hip/hip_runtime.h>

#define N_NODES 20000
#define N_EDGES 8192
#define DIM 128
#define NWORDS 313        // ceil(20000/64) node-words
#define XT_STRIDE 20032   // NWORDS*64, padded node dim for Xt
#define NT_STRIDE 20032   // maskNT row length in u64 (k1 writes all of it)
#define KSPLIT 8
#define WPC 40            // mask words per K-chunk in k2m (7x40 + 33)
#define ZPAD 40           // Zl row stride (ushort) in k2rz bounce
#define K3SPLIT 4         // K-chunks in k3p (32 words each)

typedef unsigned long long u64;
typedef __attribute__((ext_vector_type(8))) __bf16 bf16x8_t;
typedef __attribute__((ext_vector_type(4))) float f32x4;

__device__ __forceinline__ f32x4 mfma16(bf16x8_t a, bf16x8_t b, f32x4 c) {
  return __builtin_amdgcn_mfma_f32_16x16x32_bf16(a, b, c, 0, 0, 0);
}

// fp32 -> bf16 bits, round-to-nearest-even
__device__ __forceinline__ ushort f2bf(float f) {
  unsigned int x = __float_as_uint(f);
  unsigned int r = (x + 0x7FFFu + ((x >> 16) & 1u)) >> 16;
  return (ushort)r;
}

// expand 8 mask bits -> 8 bf16 values (1.0/0.0)
__device__ __forceinline__ bf16x8_t expand8(unsigned int byte) {
  union { unsigned int u[4]; bf16x8_t v; } A;
  const unsigned int w = byte | (byte << 15);
#pragma unroll
  for (int p = 0; p < 4; ++p) {
    A.u[p] = ((w >> (2 * p)) & 0x00010001u) * 0x3F80u;
  }
  return A.v;
}

// ---------------------------------------------------------------------------
// K0: Xt[d][n] = bf16(X[n][d]), n padded to XT_STRIDE with zeros.
// ---------------------------------------------------------------------------
__global__ __launch_bounds__(256) void k0_xt(const float* __restrict__ X,
                                             ushort* __restrict__ Xt) {
  __shared__ float T[64][129];
  const int t = threadIdx.x;
  const int n0 = blockIdx.x * 64;
#pragma unroll
  for (int i = 0; i < 32; ++i) {
    const int flat = i * 256 + t;
    const int nl = flat >> 7, d = flat & 127;
    const int n = n0 + nl;
    T[nl][d] = (n < N_NODES) ? X[(size_t)n * DIM + d] : 0.f;
  }
  __syncthreads();
  const int d = t >> 1, half = t & 1;
#pragma unroll
  for (int g = 0; g < 4; ++g) {
    union { ushort h[8]; int4 v; } u;
#pragma unroll
    for (int j = 0; j < 8; ++j) {
      const int nl = half * 32 + g * 8 + j;
      u.h[j] = f2bf(T[nl][d]);
    }
    *(int4*)&Xt[(size_t)d * XT_STRIDE + n0 + half * 32 + g * 8] = u.v;
  }
}

// ---------------------------------------------------------------------------
// K1: stream H once -> maskT[c][e], maskNT[ew][n]. Per-lane ballot capture,
// single 512B wave store for maskNT.
// ---------------------------------------------------------------------------
__global__ __launch_bounds__(256) void k1_mask(const float* __restrict__ H,
                                               u64* __restrict__ maskNT,
                                               u64* __restrict__ maskT) {
  const int tid  = threadIdx.x;
  const int wave = tid >> 6, lane = tid & 63;
  const int e  = blockIdx.x * 256 + wave * 64 + lane;
  const int n0 = blockIdx.y * 64;
  const int ew = blockIdx.x * 4 + wave;   // edge-window index 0..127

  u64 tmask = 0, myb = 0;
#pragma unroll 8
  for (int i = 0; i < 64; ++i) {
    const int n = n0 + i;
    const bool pred = (n < N_NODES) && (H[(size_t)n * N_EDGES + e] != 0.0f);
    const u64 bal = __ballot(pred);
    myb = (lane == i) ? bal : myb;          // lane i keeps ballot of iter i
    tmask |= pred ? (1ull << i) : 0ull;
  }
  maskNT[(size_t)ew * NT_STRIDE + n0 + lane] = myb;   // 512B coalesced
  maskT[(size_t)blockIdx.y * N_EDGES + e] = tmask;
}

// ---------------------------------------------------------------------------
// K_deg: DeInv / DvInv via 4-way split column popcount + LDS reduce.
// ---------------------------------------------------------------------------
__global__ __launch_bounds__(256) void k_deg(const u64* __restrict__ maskT,
                                             const u64* __restrict__ maskNT,
                                             float* __restrict__ DeInv,
                                             float* __restrict__ DvInv) {
  __shared__ int red[4][64];
  const int t = threadIdx.x, ol = t & 63, q = t >> 6;
  const int b = blockIdx.x;
  int s = 0;
  if (b < 128) {
    const int e = b * 64 + ol;
    for (int c = q; c < NWORDS; c += 4) s += __popcll(maskT[(size_t)c * N_EDGES + e]);
    red[q][ol] = s;
    __syncthreads();
    if (q == 0) {
      const int tot = red[0][ol] + red[1][ol] + red[2][ol] + red[3][ol];
      DeInv[e] = tot ? (1.0f / (float)tot) : 0.0f;
    }
  } else {
    const int n = (b - 128) * 64 + ol;
    for (int ew = q; ew < 128; ew += 4) s += __popcll(maskNT[(size_t)ew * NT_STRIDE + n]);
    red[q][ol] = s;
    __syncthreads();
    if (q == 0 && n < N_NODES) {
      const int tot = red[0][ol] + red[1][ol] + red[2][ol] + red[3][ol];
      DvInv[n] = tot ? (1.0f / (float)tot) : 0.0f;
    }
  }
}

// ---------------------------------------------------------------------------
// K2m: Mp[p][e][d] partial of (H^T X). 512 blocks = 64 e-tiles x 8 K-chunks.
// NO LDS, NO barriers: B-fragments (Xt, 5MB L2-resident) loaded directly
// from global as 16B/lane; compiler software-pipelines across K-steps.
// 2x2 wave grid, wave tile 64x64 (m=4, fn=4).
// ---------------------------------------------------------------------------
__global__ __launch_bounds__(256) void k2m(const u64* __restrict__ maskT,
                                           const ushort* __restrict__ Xt,
                                           float* __restrict__ Mp) {
  const int t = threadIdx.x, lane = t & 63, w = t >> 6;
  const int wr = w >> 1, wc = w & 1;
  const int bid = blockIdx.x;
  const int p  = bid >> 6;
  const int eb = (bid & 63) * 128;
  const int w0 = p * WPC;
  const int nsteps = min(WPC, NWORDS - w0);
  const int l15 = lane & 15, lh = lane >> 4;

  f32x4 acc[4][4];
#pragma unroll
  for (int m = 0; m < 4; ++m)
#pragma unroll
    for (int n = 0; n < 4; ++n) acc[m][n] = (f32x4){0.f, 0.f, 0.f, 0.f};

  // per-lane base pointers
  const u64* mbase = maskT + (size_t)w0 * N_EDGES + eb + wr * 64 + l15;
  // B-frag: col d = wc*64 + fn*16 + l15; k = step*64 + kh*32 + lh*8
  const ushort* bbase = Xt + (size_t)(wc * 64 + l15) * XT_STRIDE + w0 * 64 + lh * 8;

  for (int ks = 0; ks < nsteps; ++ks) {
    u64 wd[4];
#pragma unroll
    for (int m = 0; m < 4; ++m) wd[m] = mbase[(size_t)ks * N_EDGES + m * 16];

    bf16x8_t bf[2][4];
#pragma unroll
    for (int kh = 0; kh < 2; ++kh)
#pragma unroll
      for (int fn = 0; fn < 4; ++fn)
        bf[kh][fn] = *(const bf16x8_t*)&bbase[(size_t)(fn * 16) * XT_STRIDE + ks * 64 + kh * 32];

#pragma unroll
    for (int m = 0; m < 4; ++m) {
#pragma unroll
      for (int kh = 0; kh < 2; ++kh) {
        const unsigned int half = (unsigned int)(wd[m] >> (kh * 32));
        const unsigned int byte = (half >> (lh * 8)) & 0xFFu;
        const bf16x8_t a = expand8(byte);
#pragma unroll
        for (int fn = 0; fn < 4; ++fn)
          acc[m][fn] = mfma16(a, bf[kh][fn], acc[m][fn]);
      }
    }
  }

#pragma unroll
  for (int m = 0; m < 4; ++m)
#pragma unroll
    for (int fn = 0; fn < 4; ++fn)
#pragma unroll
      for (int r = 0; r < 4; ++r) {
        const int e = eb + wr * 64 + m * 16 + lh * 4 + r;
        const int d = wc * 64 + fn * 16 + l15;
        Mp[((size_t)p * N_EDGES + e) * DIM + d] = acc[m][fn][r];
      }
}

// ---------------------------------------------------------------------------
// K2rz: M-row = (sum_p Mp) * DeInv (bf16);  Z = M @ W^T (MFMA);
//       Zt[o][e] = bf16(Z[e][o]). 256 blocks x 32 e.
// ---------------------------------------------------------------------------
__global__ __launch_bounds__(256) void k2rz(const float* __restrict__ Mp,
                                            const float* __restrict__ DeInv,
                                            const float* __restrict__ W,
                                            ushort* __restrict__ Zt) {
  __shared__ __align__(16) ushort Wb[16384];   // slot(o,sd)=o*16+(sd^(o&7)), 8 ushort
  __shared__ __align__(16) ushort Mb[5120];    // union: A-tile (4096) / Zl[128][ZPAD]
  const int t = threadIdx.x, lane = t & 63, w = t >> 6;
  const int l15 = lane & 15, lh = lane >> 4;
  const int eb = blockIdx.x * 32;

  // stage W as bf16 B-operand (B[k=d][col=o] = W[o][d])
#pragma unroll
  for (int i = 0; i < 8; ++i) {
    const int task = i * 256 + t;
    const int o = task >> 4, sd = task & 15;
    union { ushort h[8]; int4 v; } u;
    const float* src = W + o * DIM + sd * 8;
#pragma unroll
    for (int j = 0; j < 8; ++j) u.h[j] = f2bf(src[j]);
    *(int4*)&Wb[(o * 16 + (sd ^ (o & 7))) * 8] = u.v;
  }
  // reduce Mp partials + DeInv scale -> bf16 A-tile (32 e x 128 d), float4 loads
#pragma unroll
  for (int i = 0; i < 2; ++i) {
    const int task = i * 256 + t;
    const int el = task >> 4, sd = task & 15;
    const int e = eb + el;
    float s[8] = {0.f, 0.f, 0.f, 0.f, 0.f, 0.f, 0.f, 0.f};
#pragma unroll
    for (int p = 0; p < KSPLIT; ++p) {
      const float4* mp = (const float4*)(Mp + ((size_t)p * N_EDGES + e) * DIM + sd * 8);
      const float4 a = mp[0], b2 = mp[1];
      s[0] += a.x; s[1] += a.y; s[2] += a.z; s[3] += a.w;
      s[4] += b2.x; s[5] += b2.y; s[6] += b2.z; s[7] += b2.w;
    }
    const float sc = DeInv[e];
    union { ushort h[8]; int4 v; } u;
#pragma unroll
    for (int j = 0; j < 8; ++j) u.h[j] = f2bf(s[j] * sc);
    *(int4*)&Mb[(el * 16 + (sd ^ (el & 7))) * 8] = u.v;
  }
  __syncthreads();

  // GEMM: wave w -> e-rows (w&1)*16..+16, o-block (w>>1)*64..+64. K=128.
  const int ro = w & 1, oc = w >> 1;
  f32x4 acc[4];
#pragma unroll
  for (int fn = 0; fn < 4; ++fn) acc[fn] = (f32x4){0.f, 0.f, 0.f, 0.f};
  const int el = ro * 16 + l15;
#pragma unroll
  for (int ks = 0; ks < 4; ++ks) {
    const bf16x8_t a = *(const bf16x8_t*)&Mb[(el * 16 + ((ks * 4 + lh) ^ (el & 7))) * 8];
#pragma unroll
    for (int fn = 0; fn < 4; ++fn) {
      const int o = oc * 64 + fn * 16 + l15;
      const bf16x8_t bfr = *(const bf16x8_t*)&Wb[(o * 16 + ((ks * 4 + lh) ^ (o & 7))) * 8];
      acc[fn] = mfma16(a, bfr, acc[fn]);
    }
  }
  __syncthreads();   // all waves done reading Mb A-tile

  // acc -> Zl[o][e_l] (transpose bounce)
#pragma unroll
  for (int fn = 0; fn < 4; ++fn) {
    const int o = oc * 64 + fn * 16 + l15;
#pragma unroll
    for (int r = 0; r < 4; ++r) {
      const int elc = ro * 16 + lh * 4 + r;
      Mb[o * ZPAD + elc] = f2bf(acc[fn][r]);
    }
  }
  __syncthreads();
  // coalesced global write: Zt[o][eb..eb+32)
#pragma unroll
  for (int i = 0; i < 2; ++i) {
    const int task = i * 256 + t;
    const int o = task >> 2, g = task & 3;
    *(int4*)&Zt[(size_t)o * N_EDGES + eb + g * 8] = *(const int4*)&Mb[o * ZPAD + g * 8];
  }
}

// ---------------------------------------------------------------------------
// K3p: Yp[p][n][o] partial of (H Z). 1252 blocks = 313 row-tiles x 4 K-chunks.
// NO LDS, NO barriers: B-fragments (Zt, 2MB L2-resident) loaded directly.
// 2x2 wave grid, wave tile 32x64 (m=2, fn=4).
// ---------------------------------------------------------------------------
__global__ __launch_bounds__(256) void k3p(const u64* __restrict__ maskNT,
                                           const ushort* __restrict__ Zt,
                                           float* __restrict__ Yp) {
  const int t = threadIdx.x, lane = t & 63, w = t >> 6;
  const int wr = w >> 1, wc = w & 1;
  const int bid = blockIdx.x;
  const int p  = bid & 3;
  const int nb = (bid >> 2) * 64;
  const int kw0 = p * 32;
  const int l15 = lane & 15, lh = lane >> 4;

  f32x4 acc[2][4];
#pragma unroll
  for (int m = 0; m < 2; ++m)
#pragma unroll
    for (int fn = 0; fn < 4; ++fn) acc[m][fn] = (f32x4){0.f, 0.f, 0.f, 0.f};

  const u64* mbase = maskNT + (size_t)kw0 * NT_STRIDE + nb + wr * 32 + l15;
  // B-frag: col o = wc*64 + fn*16 + l15; k = (kw0+ks)*64 + kh*32 + lh*8
  const ushort* bbase = Zt + (size_t)(wc * 64 + l15) * N_EDGES + kw0 * 64 + lh * 8;

  for (int ks = 0; ks < 32; ++ks) {
    u64 wd[2];
#pragma unroll
    for (int m = 0; m < 2; ++m) wd[m] = mbase[(size_t)ks * NT_STRIDE + m * 16];

    bf16x8_t bf[2][4];
#pragma unroll
    for (int kh = 0; kh < 2; ++kh)
#pragma unroll
      for (int fn = 0; fn < 4; ++fn)
        bf[kh][fn] = *(const bf16x8_t*)&bbase[(size_t)(fn * 16) * N_EDGES + ks * 64 + kh * 32];

#pragma unroll
    for (int m = 0; m < 2; ++m) {
#pragma unroll
      for (int kh = 0; kh < 2; ++kh) {
        const unsigned int half = (unsigned int)(wd[m] >> (kh * 32));
        const unsigned int byte = (half >> (lh * 8)) & 0xFFu;
        const bf16x8_t a = expand8(byte);
#pragma unroll
        for (int fn = 0; fn < 4; ++fn)
          acc[m][fn] = mfma16(a, bf[kh][fn], acc[m][fn]);
      }
    }
  }

  // unguarded partial store (rows up to 20031 exist in padded Yp)
#pragma unroll
  for (int m = 0; m < 2; ++m)
#pragma unroll
    for (int fn = 0; fn < 4; ++fn)
#pragma unroll
      for (int r = 0; r < 4; ++r) {
        const int n = nb + wr * 32 + m * 16 + lh * 4 + r;
        const int o = wc * 64 + fn * 16 + l15;
        Yp[((size_t)p * XT_STRIDE + n) * DIM + o] = acc[m][fn][r];
      }
}

// ---------------------------------------------------------------------------
// K3r: out[n][o] = (sum_p Yp[p][n][o]) * DvInv[n] + b[o]. 1250 blocks exact.
// ---------------------------------------------------------------------------
__global__ __launch_bounds__(256) void k3r(const float* __restrict__ Yp,
                                           const float* __restrict__ DvInv,
                                           const float* __restrict__ bias,
                                           float* __restrict__ out) {
  const int task = blockIdx.x * 256 + threadIdx.x;   // < 320000
  const int n = task >> 4;
  const int o0 = (task & 15) * 8;
  float s[8] = {0.f, 0.f, 0.f, 0.f, 0.f, 0.f, 0.f, 0.f};
#pragma unroll
  for (int p = 0; p < K3SPLIT; ++p) {
    const float4* src = (const float4*)(Yp + ((size_t)p * XT_STRIDE + n) * DIM + o0);
    const float4 a = src[0], b2 = src[1];
    s[0] += a.x; s[1] += a.y; s[2] += a.z; s[3] += a.w;
    s[4] += b2.x; s[5] += b2.y; s[6] += b2.z; s[7] += b2.w;
  }
  const float dv = DvInv[n];
  float4 r0, r1;
  const float4 b0 = *(const float4*)(bias + o0);
  const float4 b1 = *(const float4*)(bias + o0 + 4);
  r0.x = s[0] * dv + b0.x; r0.y = s[1] * dv + b0.y;
  r0.z = s[2] * dv + b0.z; r0.w = s[3] * dv + b0.w;
  r1.x = s[4] * dv + b1.x; r1.y = s[5] * dv + b1.y;
  r1.z = s[6] * dv + b1.z; r1.w = s[7] * dv + b1.w;
  float4* dst = (float4*)(out + (size_t)n * DIM + o0);
  dst[0] = r0; dst[1] = r1;
}

// ---------------------------------------------------------------------------
extern "C" void kernel_launch(void* const* d_in, const int* in_sizes, int n_in,
                              void* d_out, int out_size, void* d_ws, size_t ws_size,
                              hipStream_t stream) {
  const float* X = (const float*)d_in[0];
  const float* H = (const float*)d_in[1];
  const float* W = (const float*)d_in[2];
  const float* b = (const float*)d_in[3];
  float* out = (float*)d_out;

  char* ws = (char*)d_ws;
  u64*    maskT  = (u64*)(ws + 0);            // 313*8192*8    = 20,512,768
  u64*    maskNT = (u64*)(ws + 20512768);     // 128*20032*8   = 20,512,768
  ushort* Xt     = (ushort*)(ws + 41025536);  // 128*20032*2   =  5,128,192
  float*  Mp     = (float*)(ws + 46153728);   // 8*8192*128*4  = 33,554,432
  ushort* Zt     = (ushort*)(ws + 79708160);  // 128*8192*2    =  2,097,152
  float*  Yp     = (float*)(ws + 81805312);   // 4*20032*128*4 = 41,025,536
  float*  DeInv  = (float*)(ws + 122830848);  // 32,768
  float*  DvInv  = (float*)(ws + 122863616);  // 80,000 (end ~123 MB)

  k0_xt  <<<313, 256, 0, stream>>>(X, Xt);
  k1_mask<<<dim3(32, 313), 256, 0, stream>>>(H, maskNT, maskT);
  k_deg  <<<441, 256, 0, stream>>>(maskT, maskNT, DeInv, DvInv);
  k2m    <<<512, 256, 0, stream>>>(maskT, Xt, Mp);
  k2rz   <<<256, 256, 0, stream>>>(Mp, DeInv, W, Zt);
  k3p    <<<1252, 256, 0, stream>>>(maskNT, Zt, Yp);
  k3r    <<<1250, 256, 0, stream>>>(Yp, DvInv, b, out);
}

// Round 8
// 384.051 us; speedup vs baseline: 1.3447x; 1.3447x over previous
//
#include <hip/hip_runtime.h>

#define N_NODES 20000
#define N_EDGES 8192
#define DIM 128
#define NWORDS 313        // ceil(20000/64) node-words
#define XT_STRIDE 20032   // NWORDS*64, padded node dim for Xt
#define NT2 20096         // maskNT row stride (157*128), cols >=20032 unwritten
#define YP_STRIDE 20096   // Yp row capacity (157*128)
#define KSPLIT 8
#define WPC 40            // mask words per K-chunk in k2m (7x40 + 33)
#define ZPAD 40           // Zl row stride (ushort) in k2rz bounce
#define K3SPLIT 4         // K-chunks in k3p (32 words each)

typedef unsigned long long u64;
typedef __attribute__((ext_vector_type(8))) __bf16 bf16x8_t;
typedef __attribute__((ext_vector_type(4))) float f32x4;

__device__ __forceinline__ f32x4 mfma16(bf16x8_t a, bf16x8_t b, f32x4 c) {
  return __builtin_amdgcn_mfma_f32_16x16x32_bf16(a, b, c, 0, 0, 0);
}

__device__ __forceinline__ ushort f2bf(float f) {
  unsigned int x = __float_as_uint(f);
  unsigned int r = (x + 0x7FFFu + ((x >> 16) & 1u)) >> 16;
  return (ushort)r;
}

__device__ __forceinline__ bf16x8_t expand8(unsigned int byte) {
  union { unsigned int u[4]; bf16x8_t v; } A;
  const unsigned int w = byte | (byte << 15);
#pragma unroll
  for (int p = 0; p < 4; ++p) {
    A.u[p] = ((w >> (2 * p)) & 0x00010001u) * 0x3F80u;
  }
  return A.v;
}

#define GLOAD_LDS16(g, l)                                                  \
  __builtin_amdgcn_global_load_lds(                                        \
      (const __attribute__((address_space(1))) void*)(g),                  \
      (__attribute__((address_space(3))) void*)(l), 16, 0, 0)
#define GLOAD_LDS4(g, l)                                                   \
  __builtin_amdgcn_global_load_lds(                                        \
      (const __attribute__((address_space(1))) void*)(g),                  \
      (__attribute__((address_space(3))) void*)(l), 4, 0, 0)

// fenced raw barrier: no vmcnt drain, compiler may not hoist memory ops across
#define FENCED_BARRIER()                          \
  do {                                            \
    asm volatile("" ::: "memory");                \
    __builtin_amdgcn_s_barrier();                 \
    asm volatile("" ::: "memory");                \
  } while (0)

// ---------------------------------------------------------------------------
// K0: Xt[d][n] = bf16(X[n][d]), n padded to XT_STRIDE with zeros.
// ---------------------------------------------------------------------------
__global__ __launch_bounds__(256) void k0_xt(const float* __restrict__ X,
                                             ushort* __restrict__ Xt) {
  __shared__ float T[64][129];
  const int t = threadIdx.x;
  const int n0 = blockIdx.x * 64;
#pragma unroll
  for (int i = 0; i < 32; ++i) {
    const int flat = i * 256 + t;
    const int nl = flat >> 7, d = flat & 127;
    const int n = n0 + nl;
    T[nl][d] = (n < N_NODES) ? X[(size_t)n * DIM + d] : 0.f;
  }
  __syncthreads();
  const int d = t >> 1, half = t & 1;
#pragma unroll
  for (int g = 0; g < 4; ++g) {
    union { ushort h[8]; int4 v; } u;
#pragma unroll
    for (int j = 0; j < 8; ++j) {
      const int nl = half * 32 + g * 8 + j;
      u.h[j] = f2bf(T[nl][d]);
    }
    *(int4*)&Xt[(size_t)d * XT_STRIDE + n0 + half * 32 + g * 8] = u.v;
  }
}

// ---------------------------------------------------------------------------
// K1: stream H once -> maskT[c][e], maskNT[ew][n].
// ---------------------------------------------------------------------------
__global__ __launch_bounds__(256) void k1_mask(const float* __restrict__ H,
                                               u64* __restrict__ maskNT,
                                               u64* __restrict__ maskT) {
  const int tid  = threadIdx.x;
  const int wave = tid >> 6, lane = tid & 63;
  const int e  = blockIdx.x * 256 + wave * 64 + lane;
  const int n0 = blockIdx.y * 64;
  const int ew = blockIdx.x * 4 + wave;   // edge-window index 0..127

  u64 tmask = 0, myb = 0;
#pragma unroll 8
  for (int i = 0; i < 64; ++i) {
    const int n = n0 + i;
    const bool pred = (n < N_NODES) && (H[(size_t)n * N_EDGES + e] != 0.0f);
    const u64 bal = __ballot(pred);
    myb = (lane == i) ? bal : myb;
    tmask |= pred ? (1ull << i) : 0ull;
  }
  maskNT[(size_t)ew * NT2 + n0 + lane] = myb;   // 512B coalesced
  maskT[(size_t)blockIdx.y * N_EDGES + e] = tmask;
}

// ---------------------------------------------------------------------------
// K_deg: DeInv / DvInv via 4-way split column popcount + LDS reduce.
// ---------------------------------------------------------------------------
__global__ __launch_bounds__(256) void k_deg(const u64* __restrict__ maskT,
                                             const u64* __restrict__ maskNT,
                                             float* __restrict__ DeInv,
                                             float* __restrict__ DvInv) {
  __shared__ int red[4][64];
  const int t = threadIdx.x, ol = t & 63, q = t >> 6;
  const int b = blockIdx.x;
  int s = 0;
  if (b < 128) {
    const int e = b * 64 + ol;
    for (int c = q; c < NWORDS; c += 4) s += __popcll(maskT[(size_t)c * N_EDGES + e]);
    red[q][ol] = s;
    __syncthreads();
    if (q == 0) {
      const int tot = red[0][ol] + red[1][ol] + red[2][ol] + red[3][ol];
      DeInv[e] = tot ? (1.0f / (float)tot) : 0.0f;
    }
  } else {
    const int n = (b - 128) * 64 + ol;
    for (int ew = q; ew < 128; ew += 4) s += __popcll(maskNT[(size_t)ew * NT2 + n]);
    red[q][ol] = s;
    __syncthreads();
    if (q == 0 && n < N_NODES) {
      const int tot = red[0][ol] + red[1][ol] + red[2][ol] + red[3][ol];
      DvInv[n] = tot ? (1.0f / (float)tot) : 0.0f;
    }
  }
}

// ---------------------------------------------------------------------------
// K2m: Mp[p][e][d] partial of (H^T X). 512 blocks = 64 e-tiles x 8 K-chunks.
// Depth-2 counted-vmcnt pipeline, 3 LDS buffers. All loop VMEM = exactly
// 5 global_load_lds per wave per step (4x16B B-tile + 1x4B/lane masks).
// 2x2 wave grid, wave tile 64x64.
// ---------------------------------------------------------------------------
__global__ __launch_bounds__(256, 2) void k2m(const u64* __restrict__ maskT,
                                              const ushort* __restrict__ Xt,
                                              float* __restrict__ Mp) {
  __shared__ __align__(16) char ldsB[3][16384];
  __shared__ __align__(8)  char ldsM[3][1024];
  const int t = threadIdx.x, lane = t & 63, w = t >> 6;
  const int wr = w >> 1, wc = w & 1;
  const int bid = blockIdx.x;
  const int p  = bid >> 6;
  const int eb = (bid & 63) * 128;
  const int w0 = p * WPC;
  const int nsteps = min(WPC, NWORDS - w0);
  const int l15 = lane & 15, lh = lane >> 4;

  f32x4 acc[4][4];
#pragma unroll
  for (int m = 0; m < 4; ++m)
#pragma unroll
    for (int n = 0; n < 4; ++n) acc[m][n] = (f32x4){0.f, 0.f, 0.f, 0.f};

  auto stage = [&](int buf, int ks) {
#pragma unroll
    for (int i = 0; i < 4; ++i) {
      const int flat = i * 256 + t;
      const int d = flat >> 3, sp = flat & 7;
      const int s = sp ^ (d & 7);                 // inverse-swizzled source
      const ushort* src = Xt + (size_t)d * XT_STRIDE + (w0 + ks) * 64 + s * 8;
      GLOAD_LDS16(src, &ldsB[buf][(i * 256 + w * 64) * 16]);
    }
    const char* msrc = (const char*)(maskT + (size_t)(w0 + ks) * N_EDGES + eb) +
                       w * 256 + lane * 4;
    GLOAD_LDS4(msrc, &ldsM[buf][w * 256]);
  };

  stage(0, 0);
  stage(1, 1);
  int buf = 0;
  for (int ks = 0; ks < nsteps; ++ks) {
    if (ks + 2 < nsteps) stage((ks + 2) % 3, ks + 2);
    const int ahead = min(nsteps - 1 - ks, 2);
    if (ahead == 2)      asm volatile("s_waitcnt vmcnt(10)" ::: "memory");
    else if (ahead == 1) asm volatile("s_waitcnt vmcnt(5)" ::: "memory");
    else                 asm volatile("s_waitcnt vmcnt(0)" ::: "memory");
    __builtin_amdgcn_s_barrier();
    __builtin_amdgcn_sched_barrier(0);

    const u64* mrow = (const u64*)&ldsM[buf][0];
    u64 wd[4];
#pragma unroll
    for (int m = 0; m < 4; ++m) wd[m] = mrow[wr * 64 + m * 16 + l15];

    bf16x8_t bf[2][4];
#pragma unroll
    for (int kh = 0; kh < 2; ++kh)
#pragma unroll
      for (int fn = 0; fn < 4; ++fn) {
        const int c = wc * 64 + fn * 16 + l15;
        const int s = kh * 4 + lh;
        const int slot = 8 * c + (s ^ (c & 7));   // swizzled read
        bf[kh][fn] = *(const bf16x8_t*)&ldsB[buf][slot * 16];
      }
#pragma unroll
    for (int m = 0; m < 4; ++m) {
#pragma unroll
      for (int kh = 0; kh < 2; ++kh) {
        const unsigned int half = (unsigned int)(wd[m] >> (kh * 32));
        const unsigned int byte = (half >> (lh * 8)) & 0xFFu;
        const bf16x8_t a = expand8(byte);
#pragma unroll
        for (int fn = 0; fn < 4; ++fn)
          acc[m][fn] = mfma16(a, bf[kh][fn], acc[m][fn]);
      }
    }
    FENCED_BARRIER();     // all waves done reading buf before it is restaged
    buf = (buf + 1) % 3;
  }

#pragma unroll
  for (int m = 0; m < 4; ++m)
#pragma unroll
    for (int fn = 0; fn < 4; ++fn)
#pragma unroll
      for (int r = 0; r < 4; ++r) {
        const int e = eb + wr * 64 + m * 16 + lh * 4 + r;
        const int d = wc * 64 + fn * 16 + l15;
        Mp[((size_t)p * N_EDGES + e) * DIM + d] = acc[m][fn][r];
      }
}

// ---------------------------------------------------------------------------
// K2rz: M-row = (sum_p Mp) * DeInv (bf16);  Z = M @ W^T (MFMA);
//       Zt[o][e] = bf16(Z[e][o]). 256 blocks x 32 e.
// ---------------------------------------------------------------------------
__global__ __launch_bounds__(256) void k2rz(const float* __restrict__ Mp,
                                            const float* __restrict__ DeInv,
                                            const float* __restrict__ W,
                                            ushort* __restrict__ Zt) {
  __shared__ __align__(16) ushort Wb[16384];
  __shared__ __align__(16) ushort Mb[5120];    // union: A-tile (4096) / Zl[128][ZPAD]
  const int t = threadIdx.x, lane = t & 63, w = t >> 6;
  const int l15 = lane & 15, lh = lane >> 4;
  const int eb = blockIdx.x * 32;

#pragma unroll
  for (int i = 0; i < 8; ++i) {
    const int task = i * 256 + t;
    const int o = task >> 4, sd = task & 15;
    union { ushort h[8]; int4 v; } u;
    const float* src = W + o * DIM + sd * 8;
#pragma unroll
    for (int j = 0; j < 8; ++j) u.h[j] = f2bf(src[j]);
    *(int4*)&Wb[(o * 16 + (sd ^ (o & 7))) * 8] = u.v;
  }
#pragma unroll
  for (int i = 0; i < 2; ++i) {
    const int task = i * 256 + t;
    const int el = task >> 4, sd = task & 15;
    const int e = eb + el;
    float s[8] = {0.f, 0.f, 0.f, 0.f, 0.f, 0.f, 0.f, 0.f};
#pragma unroll
    for (int p = 0; p < KSPLIT; ++p) {
      const float4* mp = (const float4*)(Mp + ((size_t)p * N_EDGES + e) * DIM + sd * 8);
      const float4 a = mp[0], b2 = mp[1];
      s[0] += a.x; s[1] += a.y; s[2] += a.z; s[3] += a.w;
      s[4] += b2.x; s[5] += b2.y; s[6] += b2.z; s[7] += b2.w;
    }
    const float sc = DeInv[e];
    union { ushort h[8]; int4 v; } u;
#pragma unroll
    for (int j = 0; j < 8; ++j) u.h[j] = f2bf(s[j] * sc);
    *(int4*)&Mb[(el * 16 + (sd ^ (el & 7))) * 8] = u.v;
  }
  __syncthreads();

  const int ro = w & 1, oc = w >> 1;
  f32x4 acc[4];
#pragma unroll
  for (int fn = 0; fn < 4; ++fn) acc[fn] = (f32x4){0.f, 0.f, 0.f, 0.f};
  const int el = ro * 16 + l15;
#pragma unroll
  for (int ks = 0; ks < 4; ++ks) {
    const bf16x8_t a = *(const bf16x8_t*)&Mb[(el * 16 + ((ks * 4 + lh) ^ (el & 7))) * 8];
#pragma unroll
    for (int fn = 0; fn < 4; ++fn) {
      const int o = oc * 64 + fn * 16 + l15;
      const bf16x8_t bfr = *(const bf16x8_t*)&Wb[(o * 16 + ((ks * 4 + lh) ^ (o & 7))) * 8];
      acc[fn] = mfma16(a, bfr, acc[fn]);
    }
  }
  __syncthreads();

#pragma unroll
  for (int fn = 0; fn < 4; ++fn) {
    const int o = oc * 64 + fn * 16 + l15;
#pragma unroll
    for (int r = 0; r < 4; ++r) {
      const int elc = ro * 16 + lh * 4 + r;
      Mb[o * ZPAD + elc] = f2bf(acc[fn][r]);
    }
  }
  __syncthreads();
#pragma unroll
  for (int i = 0; i < 2; ++i) {
    const int task = i * 256 + t;
    const int o = task >> 2, g = task & 3;
    *(int4*)&Zt[(size_t)o * N_EDGES + eb + g * 8] = *(const int4*)&Mb[o * ZPAD + g * 8];
  }
}

// ---------------------------------------------------------------------------
// K3p: Yp[p][n][o] partial of (H Z). 628 blocks = 157 row-tiles x 4 K-chunks.
// BM=128, same depth-2 counted-vmcnt pipeline as k2m. Wave tile 64x64.
// Rows >= 20000 produce garbage into Yp pad rows (never read by k3r).
// ---------------------------------------------------------------------------
__global__ __launch_bounds__(256, 2) void k3p(const u64* __restrict__ maskNT,
                                              const ushort* __restrict__ Zt,
                                              float* __restrict__ Yp) {
  __shared__ __align__(16) char ldsB[3][16384];
  __shared__ __align__(8)  char ldsM[3][1024];
  const int t = threadIdx.x, lane = t & 63, w = t >> 6;
  const int wr = w >> 1, wc = w & 1;
  const int bid = blockIdx.x;
  const int p  = bid & 3;
  const int nb = (bid >> 2) * 128;
  const int kw0 = p * 32;
  const int l15 = lane & 15, lh = lane >> 4;

  f32x4 acc[4][4];
#pragma unroll
  for (int m = 0; m < 4; ++m)
#pragma unroll
    for (int n = 0; n < 4; ++n) acc[m][n] = (f32x4){0.f, 0.f, 0.f, 0.f};

  auto stage = [&](int buf, int ks) {
#pragma unroll
    for (int i = 0; i < 4; ++i) {
      const int flat = i * 256 + t;
      const int o = flat >> 3, sp = flat & 7;
      const int s = sp ^ (o & 7);
      const ushort* src = Zt + (size_t)o * N_EDGES + (kw0 + ks) * 64 + s * 8;
      GLOAD_LDS16(src, &ldsB[buf][(i * 256 + w * 64) * 16]);
    }
    const char* msrc = (const char*)(maskNT + (size_t)(kw0 + ks) * NT2 + nb) +
                       w * 256 + lane * 4;
    GLOAD_LDS4(msrc, &ldsM[buf][w * 256]);
  };

  stage(0, 0);
  stage(1, 1);
  int buf = 0;
  for (int ks = 0; ks < 32; ++ks) {
    if (ks + 2 < 32) stage((ks + 2) % 3, ks + 2);
    const int ahead = min(31 - ks, 2);
    if (ahead == 2)      asm volatile("s_waitcnt vmcnt(10)" ::: "memory");
    else if (ahead == 1) asm volatile("s_waitcnt vmcnt(5)" ::: "memory");
    else                 asm volatile("s_waitcnt vmcnt(0)" ::: "memory");
    __builtin_amdgcn_s_barrier();
    __builtin_amdgcn_sched_barrier(0);

    const u64* mrow = (const u64*)&ldsM[buf][0];
    u64 wd[4];
#pragma unroll
    for (int m = 0; m < 4; ++m) wd[m] = mrow[wr * 64 + m * 16 + l15];

    bf16x8_t bf[2][4];
#pragma unroll
    for (int kh = 0; kh < 2; ++kh)
#pragma unroll
      for (int fn = 0; fn < 4; ++fn) {
        const int c = wc * 64 + fn * 16 + l15;
        const int s = kh * 4 + lh;
        const int slot = 8 * c + (s ^ (c & 7));
        bf[kh][fn] = *(const bf16x8_t*)&ldsB[buf][slot * 16];
      }
#pragma unroll
    for (int m = 0; m < 4; ++m) {
#pragma unroll
      for (int kh = 0; kh < 2; ++kh) {
        const unsigned int half = (unsigned int)(wd[m] >> (kh * 32));
        const unsigned int byte = (half >> (lh * 8)) & 0xFFu;
        const bf16x8_t a = expand8(byte);
#pragma unroll
        for (int fn = 0; fn < 4; ++fn)
          acc[m][fn] = mfma16(a, bf[kh][fn], acc[m][fn]);
      }
    }
    FENCED_BARRIER();
    buf = (buf + 1) % 3;
  }

#pragma unroll
  for (int m = 0; m < 4; ++m)
#pragma unroll
    for (int fn = 0; fn < 4; ++fn)
#pragma unroll
      for (int r = 0; r < 4; ++r) {
        const int n = nb + wr * 64 + m * 16 + lh * 4 + r;   // < 20096
        const int o = wc * 64 + fn * 16 + l15;
        Yp[((size_t)p * YP_STRIDE + n) * DIM + o] = acc[m][fn][r];
      }
}

// ---------------------------------------------------------------------------
// K3r: out[n][o] = (sum_p Yp[p][n][o]) * DvInv[n] + b[o]. 1250 blocks exact.
// ---------------------------------------------------------------------------
__global__ __launch_bounds__(256) void k3r(const float* __restrict__ Yp,
                                           const float* __restrict__ DvInv,
                                           const float* __restrict__ bias,
                                           float* __restrict__ out) {
  const int task = blockIdx.x * 256 + threadIdx.x;   // < 320000
  const int n = task >> 4;
  const int o0 = (task & 15) * 8;
  float s[8] = {0.f, 0.f, 0.f, 0.f, 0.f, 0.f, 0.f, 0.f};
#pragma unroll
  for (int p = 0; p < K3SPLIT; ++p) {
    const float4* src = (const float4*)(Yp + ((size_t)p * YP_STRIDE + n) * DIM + o0);
    const float4 a = src[0], b2 = src[1];
    s[0] += a.x; s[1] += a.y; s[2] += a.z; s[3] += a.w;
    s[4] += b2.x; s[5] += b2.y; s[6] += b2.z; s[7] += b2.w;
  }
  const float dv = DvInv[n];
  float4 r0, r1;
  const float4 b0 = *(const float4*)(bias + o0);
  const float4 b1 = *(const float4*)(bias + o0 + 4);
  r0.x = s[0] * dv + b0.x; r0.y = s[1] * dv + b0.y;
  r0.z = s[2] * dv + b0.z; r0.w = s[3] * dv + b0.w;
  r1.x = s[4] * dv + b1.x; r1.y = s[5] * dv + b1.y;
  r1.z = s[6] * dv + b1.z; r1.w = s[7] * dv + b1.w;
  float4* dst = (float4*)(out + (size_t)n * DIM + o0);
  dst[0] = r0; dst[1] = r1;
}

// ---------------------------------------------------------------------------
extern "C" void kernel_launch(void* const* d_in, const int* in_sizes, int n_in,
                              void* d_out, int out_size, void* d_ws, size_t ws_size,
                              hipStream_t stream) {
  const float* X = (const float*)d_in[0];
  const float* H = (const float*)d_in[1];
  const float* W = (const float*)d_in[2];
  const float* b = (const float*)d_in[3];
  float* out = (float*)d_out;

  char* ws = (char*)d_ws;
  u64*    maskT  = (u64*)(ws + 0);             // 313*8192*8    = 20,512,768
  u64*    maskNT = (u64*)(ws + 20512768);      // 128*20096*8   = 20,578,304
  ushort* Xt     = (ushort*)(ws + 41091072);   // 128*20032*2   =  5,128,192
  float*  Mp     = (float*)(ws + 46219264);    // 8*8192*128*4  = 33,554,432
  ushort* Zt     = (ushort*)(ws + 79773696);   // 128*8192*2    =  2,097,152
  float*  Yp     = (float*)(ws + 81870848);    // 4*20096*128*4 = 41,156,608
  float*  DeInv  = (float*)(ws + 123027456);   // 32,768
  float*  DvInv  = (float*)(ws + 123060224);   // 80,000 (end ~123.1 MB)

  k0_xt  <<<313, 256, 0, stream>>>(X, Xt);
  k1_mask<<<dim3(32, 313), 256, 0, stream>>>(H, maskNT, maskT);
  k_deg  <<<441, 256, 0, stream>>>(maskT, maskNT, DeInv, DvInv);
  k2m    <<<512, 256, 0, stream>>>(maskT, Xt, Mp);
  k2rz   <<<256, 256, 0, stream>>>(Mp, DeInv, W, Zt);
  k3p    <<<628, 256, 0, stream>>>(maskNT, Zt, Yp);
  k3r    <<<1250, 256, 0, stream>>>(Yp, DvInv, b, out);
}

// Round 10
// 367.695 us; speedup vs baseline: 1.4046x; 1.0445x over previous
//
#include <hip/hip_runtime.h>

#define N_NODES 20000
#define N_EDGES 8192
#define DIM 128
#define NWORDS 313        // ceil(20000/64) node-words (K-dim of k2m)
#define EWORDS 128        // 8192/64 edge-words (K-dim of k3p)
#define XT_STRIDE 20032   // NWORDS*64, padded node dim for Xt
#define NT2 20224         // maskNT row stride (79*256); cols >=20032 unwritten garbage
#define YP_ROWS 20224     // Yp row capacity (79*256)
#define KSPLIT 8
#define WPC 40            // node-words per K-chunk in k2m (7x40 + 33)
#define ZPAD 40           // Zl row stride (ushort) in k2rz bounce
#define K3SPLIT 3         // K-chunks in k3p: 43,43,42 edge-words

typedef unsigned long long u64;
typedef __attribute__((ext_vector_type(8))) __bf16 bf16x8_t;
typedef __attribute__((ext_vector_type(4))) float f32x4;

__device__ __forceinline__ f32x4 mfma16(bf16x8_t a, bf16x8_t b, f32x4 c) {
  return __builtin_amdgcn_mfma_f32_16x16x32_bf16(a, b, c, 0, 0, 0);
}

__device__ __forceinline__ ushort f2bf(float f) {
  unsigned int x = __float_as_uint(f);
  unsigned int r = (x + 0x7FFFu + ((x >> 16) & 1u)) >> 16;
  return (ushort)r;
}

__device__ __forceinline__ bf16x8_t expand8(unsigned int byte) {
  union { unsigned int u[4]; bf16x8_t v; } A;
  const unsigned int w = byte | (byte << 15);
#pragma unroll
  for (int p = 0; p < 4; ++p) {
    A.u[p] = ((w >> (2 * p)) & 0x00010001u) * 0x3F80u;
  }
  return A.v;
}

#define GLOAD_LDS16(g, l)                                                  \
  __builtin_amdgcn_global_load_lds(                                        \
      (const __attribute__((address_space(1))) void*)(g),                  \
      (__attribute__((address_space(3))) void*)(l), 16, 0, 0)
#define GLOAD_LDS4(g, l)                                                   \
  __builtin_amdgcn_global_load_lds(                                        \
      (const __attribute__((address_space(1))) void*)(g),                  \
      (__attribute__((address_space(3))) void*)(l), 4, 0, 0)

#define FENCED_BARRIER()                          \
  do {                                            \
    asm volatile("" ::: "memory");                \
    __builtin_amdgcn_s_barrier();                 \
    asm volatile("" ::: "memory");                \
  } while (0)

// ---------------------------------------------------------------------------
// K0: Xt[d][n] = bf16(X[n][d]), n padded to XT_STRIDE with zeros.
// ---------------------------------------------------------------------------
__global__ __launch_bounds__(256) void k0_xt(const float* __restrict__ X,
                                             ushort* __restrict__ Xt) {
  __shared__ float T[64][129];
  const int t = threadIdx.x;
  const int n0 = blockIdx.x * 64;
#pragma unroll
  for (int i = 0; i < 32; ++i) {
    const int flat = i * 256 + t;
    const int nl = flat >> 7, d = flat & 127;
    const int n = n0 + nl;
    T[nl][d] = (n < N_NODES) ? X[(size_t)n * DIM + d] : 0.f;
  }
  __syncthreads();
  const int d = t >> 1, half = t & 1;
#pragma unroll
  for (int g = 0; g < 4; ++g) {
    union { ushort h[8]; int4 v; } u;
#pragma unroll
    for (int j = 0; j < 8; ++j) {
      const int nl = half * 32 + g * 8 + j;
      u.h[j] = f2bf(T[nl][d]);
    }
    *(int4*)&Xt[(size_t)d * XT_STRIDE + n0 + half * 32 + g * 8] = u.v;
  }
}

// ---------------------------------------------------------------------------
// K1: stream H once -> maskT[c][e], maskNT[ew][n].
// ---------------------------------------------------------------------------
__global__ __launch_bounds__(256) void k1_mask(const float* __restrict__ H,
                                               u64* __restrict__ maskNT,
                                               u64* __restrict__ maskT) {
  const int tid  = threadIdx.x;
  const int wave = tid >> 6, lane = tid & 63;
  const int e  = blockIdx.x * 256 + wave * 64 + lane;
  const int n0 = blockIdx.y * 64;
  const int ew = blockIdx.x * 4 + wave;   // edge-window index 0..127

  u64 tmask = 0, myb = 0;
#pragma unroll 8
  for (int i = 0; i < 64; ++i) {
    const int n = n0 + i;
    const bool pred = (n < N_NODES) && (H[(size_t)n * N_EDGES + e] != 0.0f);
    const u64 bal = __ballot(pred);
    myb = (lane == i) ? bal : myb;
    tmask |= pred ? (1ull << i) : 0ull;
  }
  maskNT[(size_t)ew * NT2 + n0 + lane] = myb;   // 512B coalesced
  maskT[(size_t)blockIdx.y * N_EDGES + e] = tmask;
}

// ---------------------------------------------------------------------------
// K2m: Mp[p][e][d] partial of (H^T X) + per-chunk column popcounts PeCnt.
// 256 blocks = 32 e-tiles(256) x 8 K-chunks. 512 threads, 8 waves (4x2),
// wave tile 64x64. Depth-2 counted-vmcnt, 3 LDS buffers.
// Per-wave VMEM per stage = 3 (2x16B B + 1x4B masks) -> vmcnt 6/3/0.
// ---------------------------------------------------------------------------
__global__ __launch_bounds__(512, 2) void k2m(const u64* __restrict__ maskT,
                                              const ushort* __restrict__ Xt,
                                              float* __restrict__ Mp,
                                              int* __restrict__ PeCnt) {
  __shared__ __align__(16) char ldsB[3][16384];
  __shared__ __align__(16) char ldsM[3][2048];
  const int t = threadIdx.x, lane = t & 63, w = t >> 6;
  const int wr = w >> 1, wc = w & 1;
  const int bid = blockIdx.x;
  const int p  = bid >> 5;
  const int eb = (bid & 31) * 256;
  const int w0 = p * WPC;
  const int nsteps = min(WPC, NWORDS - w0);
  const int l15 = lane & 15, lh = lane >> 4;

  f32x4 acc[4][4];
#pragma unroll
  for (int m = 0; m < 4; ++m)
#pragma unroll
    for (int n = 0; n < 4; ++n) acc[m][n] = (f32x4){0.f, 0.f, 0.f, 0.f};
  int cnt[4] = {0, 0, 0, 0};

  auto stage = [&](int buf, int ks) {
#pragma unroll
    for (int i = 0; i < 2; ++i) {
      const int flat = i * 512 + t;
      const int d = flat >> 3, sp = flat & 7;
      const int s = sp ^ (d & 7);                 // inverse-swizzled source
      const ushort* src = Xt + (size_t)d * XT_STRIDE + (w0 + ks) * 64 + s * 8;
      GLOAD_LDS16(src, &ldsB[buf][(i * 512 + w * 64) * 16]);
    }
    const char* msrc = (const char*)(maskT + (size_t)(w0 + ks) * N_EDGES + eb) +
                       w * 256 + lane * 4;
    GLOAD_LDS4(msrc, &ldsM[buf][w * 256]);
  };

  stage(0, 0);
  stage(1, 1);
  int buf = 0;
  for (int ks = 0; ks < nsteps; ++ks) {
    if (ks + 2 < nsteps) stage((ks + 2) % 3, ks + 2);
    const int ahead = min(nsteps - 1 - ks, 2);
    if (ahead == 2)      asm volatile("s_waitcnt vmcnt(6)" ::: "memory");
    else if (ahead == 1) asm volatile("s_waitcnt vmcnt(3)" ::: "memory");
    else                 asm volatile("s_waitcnt vmcnt(0)" ::: "memory");
    __builtin_amdgcn_s_barrier();
    __builtin_amdgcn_sched_barrier(0);

    const u64* mrow = (const u64*)&ldsM[buf][0];
    u64 wd[4];
#pragma unroll
    for (int m = 0; m < 4; ++m) {
      wd[m] = mrow[wr * 64 + m * 16 + l15];
      cnt[m] += __popcll(wd[m]);
    }

    bf16x8_t bf[2][4];
#pragma unroll
    for (int kh = 0; kh < 2; ++kh)
#pragma unroll
      for (int fn = 0; fn < 4; ++fn) {
        const int c = wc * 64 + fn * 16 + l15;
        const int s = kh * 4 + lh;
        const int slot = 8 * c + (s ^ (c & 7));   // swizzled read
        bf[kh][fn] = *(const bf16x8_t*)&ldsB[buf][slot * 16];
      }
#pragma unroll
    for (int m = 0; m < 4; ++m) {
#pragma unroll
      for (int kh = 0; kh < 2; ++kh) {
        const unsigned int half = (unsigned int)(wd[m] >> (kh * 32));
        const unsigned int byte = (half >> (lh * 8)) & 0xFFu;
        const bf16x8_t a = expand8(byte);
#pragma unroll
        for (int fn = 0; fn < 4; ++fn)
          acc[m][fn] = mfma16(a, bf[kh][fn], acc[m][fn]);
      }
    }
    FENCED_BARRIER();
    buf = (buf + 1) % 3;
  }

#pragma unroll
  for (int m = 0; m < 4; ++m)
#pragma unroll
    for (int fn = 0; fn < 4; ++fn)
#pragma unroll
      for (int r = 0; r < 4; ++r) {
        const int e = eb + wr * 64 + m * 16 + lh * 4 + r;
        const int d = wc * 64 + fn * 16 + l15;
        Mp[((size_t)p * N_EDGES + e) * DIM + d] = acc[m][fn][r];
      }
  if (lh == 0 && wc == 0) {
#pragma unroll
    for (int m = 0; m < 4; ++m)
      PeCnt[(size_t)p * N_EDGES + eb + wr * 64 + m * 16 + l15] = cnt[m];
  }
}

// ---------------------------------------------------------------------------
// K2rz: M-row = (sum_p Mp) / De (bf16);  Z = M @ W^T (MFMA);
//       Zt[o][e] = bf16(Z[e][o]). 256 blocks x 32 e. De from PeCnt.
// ---------------------------------------------------------------------------
__global__ __launch_bounds__(256) void k2rz(const float* __restrict__ Mp,
                                            const int* __restrict__ PeCnt,
                                            const float* __restrict__ W,
                                            ushort* __restrict__ Zt) {
  __shared__ __align__(16) ushort Wb[16384];
  __shared__ __align__(16) ushort Mb[5120];    // union: A-tile (4096) / Zl[128][ZPAD]
  const int t = threadIdx.x, lane = t & 63, w = t >> 6;
  const int l15 = lane & 15, lh = lane >> 4;
  const int eb = blockIdx.x * 32;

#pragma unroll
  for (int i = 0; i < 8; ++i) {
    const int task = i * 256 + t;
    const int o = task >> 4, sd = task & 15;
    union { ushort h[8]; int4 v; } u;
    const float* src = W + o * DIM + sd * 8;
#pragma unroll
    for (int j = 0; j < 8; ++j) u.h[j] = f2bf(src[j]);
    *(int4*)&Wb[(o * 16 + (sd ^ (o & 7))) * 8] = u.v;
  }
#pragma unroll
  for (int i = 0; i < 2; ++i) {
    const int task = i * 256 + t;
    const int el = task >> 4, sd = task & 15;
    const int e = eb + el;
    float s[8] = {0.f, 0.f, 0.f, 0.f, 0.f, 0.f, 0.f, 0.f};
    int tot = 0;
#pragma unroll
    for (int p = 0; p < KSPLIT; ++p) {
      const float4* mp = (const float4*)(Mp + ((size_t)p * N_EDGES + e) * DIM + sd * 8);
      const float4 a = mp[0], b2 = mp[1];
      s[0] += a.x; s[1] += a.y; s[2] += a.z; s[3] += a.w;
      s[4] += b2.x; s[5] += b2.y; s[6] += b2.z; s[7] += b2.w;
      tot += PeCnt[(size_t)p * N_EDGES + e];
    }
    const float sc = tot ? (1.0f / (float)tot) : 0.0f;
    union { ushort h[8]; int4 v; } u;
#pragma unroll
    for (int j = 0; j < 8; ++j) u.h[j] = f2bf(s[j] * sc);
    *(int4*)&Mb[(el * 16 + (sd ^ (el & 7))) * 8] = u.v;
  }
  __syncthreads();

  const int ro = w & 1, oc = w >> 1;
  f32x4 acc[4];
#pragma unroll
  for (int fn = 0; fn < 4; ++fn) acc[fn] = (f32x4){0.f, 0.f, 0.f, 0.f};
  const int el = ro * 16 + l15;
#pragma unroll
  for (int ks = 0; ks < 4; ++ks) {
    const bf16x8_t a = *(const bf16x8_t*)&Mb[(el * 16 + ((ks * 4 + lh) ^ (el & 7))) * 8];
#pragma unroll
    for (int fn = 0; fn < 4; ++fn) {
      const int o = oc * 64 + fn * 16 + l15;
      const bf16x8_t bfr = *(const bf16x8_t*)&Wb[(o * 16 + ((ks * 4 + lh) ^ (o & 7))) * 8];
      acc[fn] = mfma16(a, bfr, acc[fn]);
    }
  }
  __syncthreads();

#pragma unroll
  for (int fn = 0; fn < 4; ++fn) {
    const int o = oc * 64 + fn * 16 + l15;
#pragma unroll
    for (int r = 0; r < 4; ++r) {
      const int elc = ro * 16 + lh * 4 + r;
      Mb[o * ZPAD + elc] = f2bf(acc[fn][r]);
    }
  }
  __syncthreads();
#pragma unroll
  for (int i = 0; i < 2; ++i) {
    const int task = i * 256 + t;
    const int o = task >> 2, g = task & 3;
    *(int4*)&Zt[(size_t)o * N_EDGES + eb + g * 8] = *(const int4*)&Mb[o * ZPAD + g * 8];
  }
}

// ---------------------------------------------------------------------------
// K3p: Yp[p][n][o] partial of (H Z) + per-chunk row popcounts PnCnt.
// 237 blocks = 79 n-tiles(256) x 3 K-chunks over the 128 EDGE-words
// (43,43,42 words). 512 threads, wave tile 64x64 (4x2). Same pipeline as k2m.
// Rows >= 20000 compute garbage into Yp pad rows (never read by k3r).
// ---------------------------------------------------------------------------
__global__ __launch_bounds__(512, 2) void k3p(const u64* __restrict__ maskNT,
                                              const ushort* __restrict__ Zt,
                                              float* __restrict__ Yp,
                                              int* __restrict__ PnCnt) {
  __shared__ __align__(16) char ldsB[3][16384];
  __shared__ __align__(16) char ldsM[3][2048];
  const int t = threadIdx.x, lane = t & 63, w = t >> 6;
  const int wr = w >> 1, wc = w & 1;
  const int bid = blockIdx.x;
  const int p  = bid / 79;
  const int nb = (bid % 79) * 256;
  const int kw0 = p * 43;                       // K-chunks over EWORDS=128
  const int nsteps = (p == 2) ? 42 : 43;        // 43+43+42 = 128
  const int l15 = lane & 15, lh = lane >> 4;

  f32x4 acc[4][4];
#pragma unroll
  for (int m = 0; m < 4; ++m)
#pragma unroll
    for (int n = 0; n < 4; ++n) acc[m][n] = (f32x4){0.f, 0.f, 0.f, 0.f};
  int cnt[4] = {0, 0, 0, 0};

  auto stage = [&](int buf, int ks) {
#pragma unroll
    for (int i = 0; i < 2; ++i) {
      const int flat = i * 512 + t;
      const int o = flat >> 3, sp = flat & 7;
      const int s = sp ^ (o & 7);
      const ushort* src = Zt + (size_t)o * N_EDGES + (kw0 + ks) * 64 + s * 8;
      GLOAD_LDS16(src, &ldsB[buf][(i * 512 + w * 64) * 16]);
    }
    const char* msrc = (const char*)(maskNT + (size_t)(kw0 + ks) * NT2 + nb) +
                       w * 256 + lane * 4;
    GLOAD_LDS4(msrc, &ldsM[buf][w * 256]);
  };

  stage(0, 0);
  stage(1, 1);
  int buf = 0;
  for (int ks = 0; ks < nsteps; ++ks) {
    if (ks + 2 < nsteps) stage((ks + 2) % 3, ks + 2);
    const int ahead = min(nsteps - 1 - ks, 2);
    if (ahead == 2)      asm volatile("s_waitcnt vmcnt(6)" ::: "memory");
    else if (ahead == 1) asm volatile("s_waitcnt vmcnt(3)" ::: "memory");
    else                 asm volatile("s_waitcnt vmcnt(0)" ::: "memory");
    __builtin_amdgcn_s_barrier();
    __builtin_amdgcn_sched_barrier(0);

    const u64* mrow = (const u64*)&ldsM[buf][0];
    u64 wd[4];
#pragma unroll
    for (int m = 0; m < 4; ++m) {
      wd[m] = mrow[wr * 64 + m * 16 + l15];
      cnt[m] += __popcll(wd[m]);
    }

    bf16x8_t bf[2][4];
#pragma unroll
    for (int kh = 0; kh < 2; ++kh)
#pragma unroll
      for (int fn = 0; fn < 4; ++fn) {
        const int c = wc * 64 + fn * 16 + l15;
        const int s = kh * 4 + lh;
        const int slot = 8 * c + (s ^ (c & 7));
        bf[kh][fn] = *(const bf16x8_t*)&ldsB[buf][slot * 16];
      }
#pragma unroll
    for (int m = 0; m < 4; ++m) {
#pragma unroll
      for (int kh = 0; kh < 2; ++kh) {
        const unsigned int half = (unsigned int)(wd[m] >> (kh * 32));
        const unsigned int byte = (half >> (lh * 8)) & 0xFFu;
        const bf16x8_t a = expand8(byte);
#pragma unroll
        for (int fn = 0; fn < 4; ++fn)
          acc[m][fn] = mfma16(a, bf[kh][fn], acc[m][fn]);
      }
    }
    FENCED_BARRIER();
    buf = (buf + 1) % 3;
  }

#pragma unroll
  for (int m = 0; m < 4; ++m)
#pragma unroll
    for (int fn = 0; fn < 4; ++fn)
#pragma unroll
      for (int r = 0; r < 4; ++r) {
        const int n = nb + wr * 64 + m * 16 + lh * 4 + r;   // < 20224
        const int o = wc * 64 + fn * 16 + l15;
        Yp[((size_t)p * YP_ROWS + n) * DIM + o] = acc[m][fn][r];
      }
  if (lh == 0 && wc == 0) {
#pragma unroll
    for (int m = 0; m < 4; ++m)
      PnCnt[(size_t)p * YP_ROWS + nb + wr * 64 + m * 16 + l15] = cnt[m];
  }
}

// ---------------------------------------------------------------------------
// K3r: out[n][o] = (sum_p Yp[p][n][o]) / Dv[n] + b[o]. 1250 blocks exact.
// Dv from PnCnt sums.
// ---------------------------------------------------------------------------
__global__ __launch_bounds__(256) void k3r(const float* __restrict__ Yp,
                                           const int* __restrict__ PnCnt,
                                           const float* __restrict__ bias,
                                           float* __restrict__ out) {
  const int task = blockIdx.x * 256 + threadIdx.x;   // < 320000
  const int n = task >> 4;
  const int o0 = (task & 15) * 8;
  float s[8] = {0.f, 0.f, 0.f, 0.f, 0.f, 0.f, 0.f, 0.f};
  int tot = 0;
#pragma unroll
  for (int p = 0; p < K3SPLIT; ++p) {
    const float4* src = (const float4*)(Yp + ((size_t)p * YP_ROWS + n) * DIM + o0);
    const float4 a = src[0], b2 = src[1];
    s[0] += a.x; s[1] += a.y; s[2] += a.z; s[3] += a.w;
    s[4] += b2.x; s[5] += b2.y; s[6] += b2.z; s[7] += b2.w;
    tot += PnCnt[(size_t)p * YP_ROWS + n];
  }
  const float dv = tot ? (1.0f / (float)tot) : 0.0f;
  float4 r0, r1;
  const float4 b0 = *(const float4*)(bias + o0);
  const float4 b1 = *(const float4*)(bias + o0 + 4);
  r0.x = s[0] * dv + b0.x; r0.y = s[1] * dv + b0.y;
  r0.z = s[2] * dv + b0.z; r0.w = s[3] * dv + b0.w;
  r1.x = s[4] * dv + b1.x; r1.y = s[5] * dv + b1.y;
  r1.z = s[6] * dv + b1.z; r1.w = s[7] * dv + b1.w;
  float4* dst = (float4*)(out + (size_t)n * DIM + o0);
  dst[0] = r0; dst[1] = r1;
}

// ---------------------------------------------------------------------------
extern "C" void kernel_launch(void* const* d_in, const int* in_sizes, int n_in,
                              void* d_out, int out_size, void* d_ws, size_t ws_size,
                              hipStream_t stream) {
  const float* X = (const float*)d_in[0];
  const float* H = (const float*)d_in[1];
  const float* W = (const float*)d_in[2];
  const float* b = (const float*)d_in[3];
  float* out = (float*)d_out;

  char* ws = (char*)d_ws;
  u64*    maskT  = (u64*)(ws + 0);             // 313*8192*8    = 20,512,768
  u64*    maskNT = (u64*)(ws + 20512768);      // 128*20224*8   = 20,709,376
  ushort* Xt     = (ushort*)(ws + 41222144);   // 128*20032*2   =  5,128,192
  float*  Mp     = (float*)(ws + 46350336);    // 8*8192*128*4  = 33,554,432
  ushort* Zt     = (ushort*)(ws + 79904768);   // 128*8192*2    =  2,097,152
  float*  Yp     = (float*)(ws + 82001920);    // 3*20224*128*4 = 31,064,064
  int*    PeCnt  = (int*)(ws + 113065984);     // 8*8192*4      =    262,144
  int*    PnCnt  = (int*)(ws + 113328128);     // 3*20224*4     =    242,688

  k0_xt  <<<313, 256, 0, stream>>>(X, Xt);
  k1_mask<<<dim3(32, 313), 256, 0, stream>>>(H, maskNT, maskT);
  k2m    <<<256, 512, 0, stream>>>(maskT, Xt, Mp, PeCnt);
  k2rz   <<<256, 256, 0, stream>>>(Mp, PeCnt, W, Zt);
  k3p    <<<237, 512, 0, stream>>>(maskNT, Zt, Yp, PnCnt);
  k3r    <<<1250, 256, 0, stream>>>(Yp, PnCnt, b, out);
}

// Round 11
// 337.873 us; speedup vs baseline: 1.5285x; 1.0883x over previous
//
#include <hip/hip_runtime.h>

#define N_NODES 20000
#define N_EDGES 8192
#define DIM 128
#define NWORDS 313        // ceil(20000/64) node-words (K-dim of k2m)
#define EWORDS 128        // 8192/64 edge-words (K-dim of k3p)
#define XT_STRIDE 20032   // NWORDS*64, padded node dim for Xt
#define NT2 20224         // maskNT row stride (79*256); cols >=20032 unwritten garbage
#define YP_ROWS 20224     // Yp row capacity (79*256)
#define KSPLIT 16         // K-chunks in k2m: 15x20 + 13 node-words
#define WPC 20
#define ZPAD 40           // Zl row stride (ushort) in k2rz bounce
#define K3SPLIT 6         // K-chunks in k3p: 5x22 + 18 edge-words
#define W3PC 22

typedef unsigned long long u64;
typedef __attribute__((ext_vector_type(8))) __bf16 bf16x8_t;
typedef __attribute__((ext_vector_type(4))) float f32x4;

__device__ __forceinline__ f32x4 mfma16(bf16x8_t a, bf16x8_t b, f32x4 c) {
  return __builtin_amdgcn_mfma_f32_16x16x32_bf16(a, b, c, 0, 0, 0);
}

__device__ __forceinline__ ushort f2bf(float f) {
  unsigned int x = __float_as_uint(f);
  unsigned int r = (x + 0x7FFFu + ((x >> 16) & 1u)) >> 16;
  return (ushort)r;
}
__device__ __forceinline__ float bf2f(ushort h) {
  return __uint_as_float(((unsigned int)h) << 16);
}

__device__ __forceinline__ bf16x8_t expand8(unsigned int byte) {
  union { unsigned int u[4]; bf16x8_t v; } A;
  const unsigned int w = byte | (byte << 15);
#pragma unroll
  for (int p = 0; p < 4; ++p) {
    A.u[p] = ((w >> (2 * p)) & 0x00010001u) * 0x3F80u;
  }
  return A.v;
}

#define GLOAD_LDS16(g, l)                                                  \
  __builtin_amdgcn_global_load_lds(                                        \
      (const __attribute__((address_space(1))) void*)(g),                  \
      (__attribute__((address_space(3))) void*)(l), 16, 0, 0)
#define GLOAD_LDS4(g, l)                                                   \
  __builtin_amdgcn_global_load_lds(                                        \
      (const __attribute__((address_space(1))) void*)(g),                  \
      (__attribute__((address_space(3))) void*)(l), 4, 0, 0)

#define FENCED_BARRIER()                          \
  do {                                            \
    asm volatile("" ::: "memory");                \
    __builtin_amdgcn_s_barrier();                 \
    asm volatile("" ::: "memory");                \
  } while (0)

// ---------------------------------------------------------------------------
// K0: Xt[d][n] = bf16(X[n][d]), n padded to XT_STRIDE with zeros.
// ---------------------------------------------------------------------------
__global__ __launch_bounds__(256) void k0_xt(const float* __restrict__ X,
                                             ushort* __restrict__ Xt) {
  __shared__ float T[64][129];
  const int t = threadIdx.x;
  const int n0 = blockIdx.x * 64;
#pragma unroll
  for (int i = 0; i < 32; ++i) {
    const int flat = i * 256 + t;
    const int nl = flat >> 7, d = flat & 127;
    const int n = n0 + nl;
    T[nl][d] = (n < N_NODES) ? X[(size_t)n * DIM + d] : 0.f;
  }
  __syncthreads();
  const int d = t >> 1, half = t & 1;
#pragma unroll
  for (int g = 0; g < 4; ++g) {
    union { ushort h[8]; int4 v; } u;
#pragma unroll
    for (int j = 0; j < 8; ++j) {
      const int nl = half * 32 + g * 8 + j;
      u.h[j] = f2bf(T[nl][d]);
    }
    *(int4*)&Xt[(size_t)d * XT_STRIDE + n0 + half * 32 + g * 8] = u.v;
  }
}

// ---------------------------------------------------------------------------
// K1: stream H once -> maskT[c][e], maskNT[ew][n].
// ---------------------------------------------------------------------------
__global__ __launch_bounds__(256) void k1_mask(const float* __restrict__ H,
                                               u64* __restrict__ maskNT,
                                               u64* __restrict__ maskT) {
  const int tid  = threadIdx.x;
  const int wave = tid >> 6, lane = tid & 63;
  const int e  = blockIdx.x * 256 + wave * 64 + lane;
  const int n0 = blockIdx.y * 64;
  const int ew = blockIdx.x * 4 + wave;   // edge-window index 0..127

  u64 tmask = 0, myb = 0;
#pragma unroll 8
  for (int i = 0; i < 64; ++i) {
    const int n = n0 + i;
    const bool pred = (n < N_NODES) && (H[(size_t)n * N_EDGES + e] != 0.0f);
    const u64 bal = __ballot(pred);
    myb = (lane == i) ? bal : myb;
    tmask |= pred ? (1ull << i) : 0ull;
  }
  maskNT[(size_t)ew * NT2 + n0 + lane] = myb;   // 512B coalesced
  maskT[(size_t)blockIdx.y * N_EDGES + e] = tmask;
}

// ---------------------------------------------------------------------------
// K2m: Mpb[p][e][d] (bf16) partial of (H^T X) + per-chunk popcounts PeCnt.
// 512 blocks = 32 e-tiles(256) x 16 K-chunks, p = bid&15 (XCD L2 locality:
// each XCD sees only 2 Xt K-slices). 512 threads, 8 waves (4x2), wave tile
// 64x64. launch_bounds(512,4) -> VGPR<=128 -> 2 blocks/CU co-resident.
// Depth-2 counted-vmcnt, 3 LDS buffers; kh-outer inner loop caps live regs.
// ---------------------------------------------------------------------------
__global__ __launch_bounds__(512, 4) void k2m(const u64* __restrict__ maskT,
                                              const ushort* __restrict__ Xt,
                                              ushort* __restrict__ Mpb,
                                              int* __restrict__ PeCnt) {
  __shared__ __align__(16) char ldsB[3][16384];
  __shared__ __align__(16) char ldsM[3][2048];
  const int t = threadIdx.x, lane = t & 63, w = t >> 6;
  const int wr = w >> 1, wc = w & 1;
  const int bid = blockIdx.x;
  const int p  = bid & 15;
  const int eb = (bid >> 4) * 256;
  const int w0 = p * WPC;
  const int nsteps = min(WPC, NWORDS - w0);
  const int l15 = lane & 15, lh = lane >> 4;

  f32x4 acc[4][4];
#pragma unroll
  for (int m = 0; m < 4; ++m)
#pragma unroll
    for (int n = 0; n < 4; ++n) acc[m][n] = (f32x4){0.f, 0.f, 0.f, 0.f};
  int cnt[4] = {0, 0, 0, 0};

  auto stage = [&](int buf, int ks) {
#pragma unroll
    for (int i = 0; i < 2; ++i) {
      const int flat = i * 512 + t;
      const int d = flat >> 3, sp = flat & 7;
      const int s = sp ^ (d & 7);                 // inverse-swizzled source
      const ushort* src = Xt + (size_t)d * XT_STRIDE + (w0 + ks) * 64 + s * 8;
      GLOAD_LDS16(src, &ldsB[buf][(i * 512 + w * 64) * 16]);
    }
    const char* msrc = (const char*)(maskT + (size_t)(w0 + ks) * N_EDGES + eb) +
                       w * 256 + lane * 4;
    GLOAD_LDS4(msrc, &ldsM[buf][w * 256]);
  };

  stage(0, 0);
  stage(1, 1);
  int buf = 0;
  for (int ks = 0; ks < nsteps; ++ks) {
    if (ks + 2 < nsteps) stage((ks + 2) % 3, ks + 2);
    const int ahead = min(nsteps - 1 - ks, 2);
    if (ahead == 2)      asm volatile("s_waitcnt vmcnt(6)" ::: "memory");
    else if (ahead == 1) asm volatile("s_waitcnt vmcnt(3)" ::: "memory");
    else                 asm volatile("s_waitcnt vmcnt(0)" ::: "memory");
    __builtin_amdgcn_s_barrier();
    __builtin_amdgcn_sched_barrier(0);

    const u64* mrow = (const u64*)&ldsM[buf][0];
    u64 wd[4];
#pragma unroll
    for (int m = 0; m < 4; ++m) {
      wd[m] = mrow[wr * 64 + m * 16 + l15];
      cnt[m] += __popcll(wd[m]);
    }

#pragma unroll
    for (int kh = 0; kh < 2; ++kh) {
      bf16x8_t bf[4];
#pragma unroll
      for (int fn = 0; fn < 4; ++fn) {
        const int c = wc * 64 + fn * 16 + l15;
        const int s = kh * 4 + lh;
        const int slot = 8 * c + (s ^ (c & 7));   // swizzled read
        bf[fn] = *(const bf16x8_t*)&ldsB[buf][slot * 16];
      }
#pragma unroll
      for (int m = 0; m < 4; ++m) {
        const unsigned int byte = (unsigned int)(wd[m] >> (kh * 32 + lh * 8)) & 0xFFu;
        const bf16x8_t a = expand8(byte);
#pragma unroll
        for (int fn = 0; fn < 4; ++fn)
          acc[m][fn] = mfma16(a, bf[fn], acc[m][fn]);
      }
    }
    FENCED_BARRIER();
    buf = (buf + 1) % 3;
  }

  // epilogue: acc -> bf16 via LDS bounce (4 phases of 64 rows x 128 cols)
  ushort* ush = (ushort*)ldsB;
#pragma unroll
  for (int m = 0; m < 4; ++m) {
#pragma unroll
    for (int fn = 0; fn < 4; ++fn)
#pragma unroll
      for (int r = 0; r < 4; ++r) {
        const int row = wr * 16 + lh * 4 + r;       // 0..63
        const int d = wc * 64 + fn * 16 + l15;
        ush[row * 128 + d] = f2bf(acc[m][fn][r]);
      }
    FENCED_BARRIER();
#pragma unroll
    for (int i = 0; i < 2; ++i) {
      const int task = i * 512 + t;                 // 0..1023 = 64 rows x 16 int4
      const int row = task >> 4, dg = task & 15;
      const int e = eb + (row >> 4) * 64 + m * 16 + (row & 15);
      *(int4*)&Mpb[((size_t)p * N_EDGES + e) * DIM + dg * 8] =
          *(const int4*)&ush[row * 128 + dg * 8];
    }
    FENCED_BARRIER();
  }
  if (lh == 0 && wc == 0) {
#pragma unroll
    for (int m = 0; m < 4; ++m)
      PeCnt[(size_t)p * N_EDGES + eb + wr * 64 + m * 16 + l15] = cnt[m];
  }
}

// ---------------------------------------------------------------------------
// K2rz: M-row = (sum_p Mpb) / De (bf16);  Z = M @ W^T (MFMA);
//       Zt[o][e] = bf16(Z[e][o]). 256 blocks x 32 e. De from PeCnt.
// ---------------------------------------------------------------------------
__global__ __launch_bounds__(256) void k2rz(const ushort* __restrict__ Mpb,
                                            const int* __restrict__ PeCnt,
                                            const float* __restrict__ W,
                                            ushort* __restrict__ Zt) {
  __shared__ __align__(16) ushort Wb[16384];
  __shared__ __align__(16) ushort Mb[5120];    // union: A-tile (4096) / Zl[128][ZPAD]
  const int t = threadIdx.x, lane = t & 63, w = t >> 6;
  const int l15 = lane & 15, lh = lane >> 4;
  const int eb = blockIdx.x * 32;

#pragma unroll
  for (int i = 0; i < 8; ++i) {
    const int task = i * 256 + t;
    const int o = task >> 4, sd = task & 15;
    union { ushort h[8]; int4 v; } u;
    const float* src = W + o * DIM + sd * 8;
#pragma unroll
    for (int j = 0; j < 8; ++j) u.h[j] = f2bf(src[j]);
    *(int4*)&Wb[(o * 16 + (sd ^ (o & 7))) * 8] = u.v;
  }
#pragma unroll
  for (int i = 0; i < 2; ++i) {
    const int task = i * 256 + t;
    const int el = task >> 4, sd = task & 15;
    const int e = eb + el;
    float s[8] = {0.f, 0.f, 0.f, 0.f, 0.f, 0.f, 0.f, 0.f};
    int tot = 0;
#pragma unroll
    for (int p = 0; p < KSPLIT; ++p) {
      union { ushort h[8]; int4 v; } u;
      u.v = *(const int4*)(Mpb + ((size_t)p * N_EDGES + e) * DIM + sd * 8);
#pragma unroll
      for (int j = 0; j < 8; ++j) s[j] += bf2f(u.h[j]);
      tot += PeCnt[(size_t)p * N_EDGES + e];
    }
    const float sc = tot ? (1.0f / (float)tot) : 0.0f;
    union { ushort h[8]; int4 v; } u;
#pragma unroll
    for (int j = 0; j < 8; ++j) u.h[j] = f2bf(s[j] * sc);
    *(int4*)&Mb[(el * 16 + (sd ^ (el & 7))) * 8] = u.v;
  }
  __syncthreads();

  const int ro = w & 1, oc = w >> 1;
  f32x4 acc[4];
#pragma unroll
  for (int fn = 0; fn < 4; ++fn) acc[fn] = (f32x4){0.f, 0.f, 0.f, 0.f};
  const int el = ro * 16 + l15;
#pragma unroll
  for (int ks = 0; ks < 4; ++ks) {
    const bf16x8_t a = *(const bf16x8_t*)&Mb[(el * 16 + ((ks * 4 + lh) ^ (el & 7))) * 8];
#pragma unroll
    for (int fn = 0; fn < 4; ++fn) {
      const int o = oc * 64 + fn * 16 + l15;
      const bf16x8_t bfr = *(const bf16x8_t*)&Wb[(o * 16 + ((ks * 4 + lh) ^ (o & 7))) * 8];
      acc[fn] = mfma16(a, bfr, acc[fn]);
    }
  }
  __syncthreads();

#pragma unroll
  for (int fn = 0; fn < 4; ++fn) {
    const int o = oc * 64 + fn * 16 + l15;
#pragma unroll
    for (int r = 0; r < 4; ++r) {
      const int elc = ro * 16 + lh * 4 + r;
      Mb[o * ZPAD + elc] = f2bf(acc[fn][r]);
    }
  }
  __syncthreads();
#pragma unroll
  for (int i = 0; i < 2; ++i) {
    const int task = i * 256 + t;
    const int o = task >> 2, g = task & 3;
    *(int4*)&Zt[(size_t)o * N_EDGES + eb + g * 8] = *(const int4*)&Mb[o * ZPAD + g * 8];
  }
}

// ---------------------------------------------------------------------------
// K3p: Ypb[p][n][o] (bf16) partial of (H Z) + per-chunk popcounts PnCnt.
// 474 blocks = 79 n-tiles(256) x 6 K-chunks (22,22,22,22,22,18 edge-words).
// 512 threads, wave tile 64x64, launch_bounds(512,4) -> ~2 blocks/CU.
// Rows >= 20000 compute garbage into pad rows (never read by k3r).
// ---------------------------------------------------------------------------
__global__ __launch_bounds__(512, 4) void k3p(const u64* __restrict__ maskNT,
                                              const ushort* __restrict__ Zt,
                                              ushort* __restrict__ Ypb,
                                              int* __restrict__ PnCnt) {
  __shared__ __align__(16) char ldsB[3][16384];
  __shared__ __align__(16) char ldsM[3][2048];
  const int t = threadIdx.x, lane = t & 63, w = t >> 6;
  const int wr = w >> 1, wc = w & 1;
  const int bid = blockIdx.x;
  const int p  = bid / 79;
  const int nb = (bid % 79) * 256;
  const int kw0 = p * W3PC;
  const int nsteps = min(W3PC, EWORDS - kw0);   // 22,...,18
  const int l15 = lane & 15, lh = lane >> 4;

  f32x4 acc[4][4];
#pragma unroll
  for (int m = 0; m < 4; ++m)
#pragma unroll
    for (int n = 0; n < 4; ++n) acc[m][n] = (f32x4){0.f, 0.f, 0.f, 0.f};
  int cnt[4] = {0, 0, 0, 0};

  auto stage = [&](int buf, int ks) {
#pragma unroll
    for (int i = 0; i < 2; ++i) {
      const int flat = i * 512 + t;
      const int o = flat >> 3, sp = flat & 7;
      const int s = sp ^ (o & 7);
      const ushort* src = Zt + (size_t)o * N_EDGES + (kw0 + ks) * 64 + s * 8;
      GLOAD_LDS16(src, &ldsB[buf][(i * 512 + w * 64) * 16]);
    }
    const char* msrc = (const char*)(maskNT + (size_t)(kw0 + ks) * NT2 + nb) +
                       w * 256 + lane * 4;
    GLOAD_LDS4(msrc, &ldsM[buf][w * 256]);
  };

  stage(0, 0);
  stage(1, 1);
  int buf = 0;
  for (int ks = 0; ks < nsteps; ++ks) {
    if (ks + 2 < nsteps) stage((ks + 2) % 3, ks + 2);
    const int ahead = min(nsteps - 1 - ks, 2);
    if (ahead == 2)      asm volatile("s_waitcnt vmcnt(6)" ::: "memory");
    else if (ahead == 1) asm volatile("s_waitcnt vmcnt(3)" ::: "memory");
    else                 asm volatile("s_waitcnt vmcnt(0)" ::: "memory");
    __builtin_amdgcn_s_barrier();
    __builtin_amdgcn_sched_barrier(0);

    const u64* mrow = (const u64*)&ldsM[buf][0];
    u64 wd[4];
#pragma unroll
    for (int m = 0; m < 4; ++m) {
      wd[m] = mrow[wr * 64 + m * 16 + l15];
      cnt[m] += __popcll(wd[m]);
    }

#pragma unroll
    for (int kh = 0; kh < 2; ++kh) {
      bf16x8_t bf[4];
#pragma unroll
      for (int fn = 0; fn < 4; ++fn) {
        const int c = wc * 64 + fn * 16 + l15;
        const int s = kh * 4 + lh;
        const int slot = 8 * c + (s ^ (c & 7));
        bf[fn] = *(const bf16x8_t*)&ldsB[buf][slot * 16];
      }
#pragma unroll
      for (int m = 0; m < 4; ++m) {
        const unsigned int byte = (unsigned int)(wd[m] >> (kh * 32 + lh * 8)) & 0xFFu;
        const bf16x8_t a = expand8(byte);
#pragma unroll
        for (int fn = 0; fn < 4; ++fn)
          acc[m][fn] = mfma16(a, bf[fn], acc[m][fn]);
      }
    }
    FENCED_BARRIER();
    buf = (buf + 1) % 3;
  }

  // epilogue: acc -> bf16 via LDS bounce (4 phases of 64 rows x 128 cols)
  ushort* ush = (ushort*)ldsB;
#pragma unroll
  for (int m = 0; m < 4; ++m) {
#pragma unroll
    for (int fn = 0; fn < 4; ++fn)
#pragma unroll
      for (int r = 0; r < 4; ++r) {
        const int row = wr * 16 + lh * 4 + r;
        const int d = wc * 64 + fn * 16 + l15;
        ush[row * 128 + d] = f2bf(acc[m][fn][r]);
      }
    FENCED_BARRIER();
#pragma unroll
    for (int i = 0; i < 2; ++i) {
      const int task = i * 512 + t;
      const int row = task >> 4, dg = task & 15;
      const int n = nb + (row >> 4) * 64 + m * 16 + (row & 15);   // < 20224
      *(int4*)&Ypb[((size_t)p * YP_ROWS + n) * DIM + dg * 8] =
          *(const int4*)&ush[row * 128 + dg * 8];
    }
    FENCED_BARRIER();
  }
  if (lh == 0 && wc == 0) {
#pragma unroll
    for (int m = 0; m < 4; ++m)
      PnCnt[(size_t)p * YP_ROWS + nb + wr * 64 + m * 16 + l15] = cnt[m];
  }
}

// ---------------------------------------------------------------------------
// K3r: out[n][o] = (sum_p Ypb[p][n][o]) / Dv[n] + b[o]. 1250 blocks exact.
// ---------------------------------------------------------------------------
__global__ __launch_bounds__(256) void k3r(const ushort* __restrict__ Ypb,
                                           const int* __restrict__ PnCnt,
                                           const float* __restrict__ bias,
                                           float* __restrict__ out) {
  const int task = blockIdx.x * 256 + threadIdx.x;   // < 320000
  const int n = task >> 4;
  const int o0 = (task & 15) * 8;
  float s[8] = {0.f, 0.f, 0.f, 0.f, 0.f, 0.f, 0.f, 0.f};
  int tot = 0;
#pragma unroll
  for (int p = 0; p < K3SPLIT; ++p) {
    union { ushort h[8]; int4 v; } u;
    u.v = *(const int4*)(Ypb + ((size_t)p * YP_ROWS + n) * DIM + o0);
#pragma unroll
    for (int j = 0; j < 8; ++j) s[j] += bf2f(u.h[j]);
    tot += PnCnt[(size_t)p * YP_ROWS + n];
  }
  const float dv = tot ? (1.0f / (float)tot) : 0.0f;
  float4 r0, r1;
  const float4 b0 = *(const float4*)(bias + o0);
  const float4 b1 = *(const float4*)(bias + o0 + 4);
  r0.x = s[0] * dv + b0.x; r0.y = s[1] * dv + b0.y;
  r0.z = s[2] * dv + b0.z; r0.w = s[3] * dv + b0.w;
  r1.x = s[4] * dv + b1.x; r1.y = s[5] * dv + b1.y;
  r1.z = s[6] * dv + b1.z; r1.w = s[7] * dv + b1.w;
  float4* dst = (float4*)(out + (size_t)n * DIM + o0);
  dst[0] = r0; dst[1] = r1;
}

// ---------------------------------------------------------------------------
extern "C" void kernel_launch(void* const* d_in, const int* in_sizes, int n_in,
                              void* d_out, int out_size, void* d_ws, size_t ws_size,
                              hipStream_t stream) {
  const float* X = (const float*)d_in[0];
  const float* H = (const float*)d_in[1];
  const float* W = (const float*)d_in[2];
  const float* b = (const float*)d_in[3];
  float* out = (float*)d_out;

  char* ws = (char*)d_ws;
  u64*    maskT  = (u64*)(ws + 0);             // 313*8192*8     = 20,512,768
  u64*    maskNT = (u64*)(ws + 20512768);      // 128*20224*8    = 20,709,376
  ushort* Xt     = (ushort*)(ws + 41222144);   // 128*20032*2    =  5,128,192
  ushort* Mpb    = (ushort*)(ws + 46350336);   // 16*8192*128*2  = 33,554,432
  ushort* Zt     = (ushort*)(ws + 79904768);   // 128*8192*2     =  2,097,152
  ushort* Ypb    = (ushort*)(ws + 82001920);   // 6*20224*128*2  = 31,064,064
  int*    PeCnt  = (int*)(ws + 113065984);     // 16*8192*4      =    524,288
  int*    PnCnt  = (int*)(ws + 113590272);     // 6*20224*4      =    485,376

  k0_xt  <<<313, 256, 0, stream>>>(X, Xt);
  k1_mask<<<dim3(32, 313), 256, 0, stream>>>(H, maskNT, maskT);
  k2m    <<<512, 512, 0, stream>>>(maskT, Xt, Mpb, PeCnt);
  k2rz   <<<256, 256, 0, stream>>>(Mpb, PeCnt, W, Zt);
  k3p    <<<474, 512, 0, stream>>>(maskNT, Zt, Ypb, PnCnt);
  k3r    <<<1250, 256, 0, stream>>>(Ypb, PnCnt, b, out);
}

// Round 12
// 278.383 us; speedup vs baseline: 1.8552x; 1.2137x over previous
//
#include <hip/hip_runtime.h>

#define N_NODES 20000
#define N_EDGES 8192
#define DIM 128
#define NWORDS 313        // ceil(20000/64) node-words (K-dim of k2m)
#define EWORDS 128        // 8192/64 edge-words (K-dim of k3p)
#define XT_STRIDE 20032   // NWORDS*64, padded node dim for Xt
#define NT2 20224         // maskNT row stride (79*256); cols >=20032 unwritten garbage
#define YP_ROWS 20224     // Yp row capacity (79*256)
#define KSPLIT 16         // K-chunks in k2m: 15x20 + 13 node-words
#define WPC 20
#define ZPAD 40           // Zl row stride (ushort) in k2rz bounce
#define K3SPLIT 6         // K-chunks in k3p: 5x22 + 18 edge-words
#define W3PC 22

typedef unsigned long long u64;
typedef __attribute__((ext_vector_type(8))) __bf16 bf16x8_t;
typedef __attribute__((ext_vector_type(4))) float f32x4;

__device__ __forceinline__ f32x4 mfma16(bf16x8_t a, bf16x8_t b, f32x4 c) {
  return __builtin_amdgcn_mfma_f32_16x16x32_bf16(a, b, c, 0, 0, 0);
}

__device__ __forceinline__ ushort f2bf(float f) {
  unsigned int x = __float_as_uint(f);
  unsigned int r = (x + 0x7FFFu + ((x >> 16) & 1u)) >> 16;
  return (ushort)r;
}
__device__ __forceinline__ float bf2f(ushort h) {
  return __uint_as_float(((unsigned int)h) << 16);
}

__device__ __forceinline__ bf16x8_t expand8(unsigned int byte) {
  union { unsigned int u[4]; bf16x8_t v; } A;
  const unsigned int w = byte | (byte << 15);
#pragma unroll
  for (int p = 0; p < 4; ++p) {
    A.u[p] = ((w >> (2 * p)) & 0x00010001u) * 0x3F80u;
  }
  return A.v;
}

#define GLOAD_LDS16(g, l)                                                  \
  __builtin_amdgcn_global_load_lds(                                        \
      (const __attribute__((address_space(1))) void*)(g),                  \
      (__attribute__((address_space(3))) void*)(l), 16, 0, 0)
#define GLOAD_LDS4(g, l)                                                   \
  __builtin_amdgcn_global_load_lds(                                        \
      (const __attribute__((address_space(1))) void*)(g),                  \
      (__attribute__((address_space(3))) void*)(l), 4, 0, 0)

#define FENCED_BARRIER()                          \
  do {                                            \
    asm volatile("" ::: "memory");                \
    __builtin_amdgcn_s_barrier();                 \
    asm volatile("" ::: "memory");                \
  } while (0)

// ---------------------------------------------------------------------------
// K0: Xt[d][n] = bf16(X[n][d]), n padded to XT_STRIDE with zeros.
// ---------------------------------------------------------------------------
__global__ __launch_bounds__(256) void k0_xt(const float* __restrict__ X,
                                             ushort* __restrict__ Xt) {
  __shared__ float T[64][129];
  const int t = threadIdx.x;
  const int n0 = blockIdx.x * 64;
#pragma unroll
  for (int i = 0; i < 32; ++i) {
    const int flat = i * 256 + t;
    const int nl = flat >> 7, d = flat & 127;
    const int n = n0 + nl;
    T[nl][d] = (n < N_NODES) ? X[(size_t)n * DIM + d] : 0.f;
  }
  __syncthreads();
  const int d = t >> 1, half = t & 1;
#pragma unroll
  for (int g = 0; g < 4; ++g) {
    union { ushort h[8]; int4 v; } u;
#pragma unroll
    for (int j = 0; j < 8; ++j) {
      const int nl = half * 32 + g * 8 + j;
      u.h[j] = f2bf(T[nl][d]);
    }
    *(int4*)&Xt[(size_t)d * XT_STRIDE + n0 + half * 32 + g * 8] = u.v;
  }
}

// ---------------------------------------------------------------------------
// K1: stream H once -> maskT[c][e], maskNT[ew][n]. Clean/guarded loop split:
// only the last y-block (rows 19968..20031) pays the bounds check.
// ---------------------------------------------------------------------------
__global__ __launch_bounds__(256) void k1_mask(const float* __restrict__ H,
                                               u64* __restrict__ maskNT,
                                               u64* __restrict__ maskT) {
  const int tid  = threadIdx.x;
  const int wave = tid >> 6, lane = tid & 63;
  const int e  = blockIdx.x * 256 + wave * 64 + lane;
  const int n0 = blockIdx.y * 64;
  const int ew = blockIdx.x * 4 + wave;   // edge-window index 0..127

  u64 tmask = 0, myb = 0;
  if (n0 + 63 < N_NODES) {
#pragma unroll 8
    for (int i = 0; i < 64; ++i) {
      const bool pred = (H[(size_t)(n0 + i) * N_EDGES + e] != 0.0f);
      const u64 bal = __ballot(pred);
      myb = (lane == i) ? bal : myb;
      tmask |= pred ? (1ull << i) : 0ull;
    }
  } else {
#pragma unroll 8
    for (int i = 0; i < 64; ++i) {
      const int n = n0 + i;
      const bool pred = (n < N_NODES) && (H[(size_t)n * N_EDGES + e] != 0.0f);
      const u64 bal = __ballot(pred);
      myb = (lane == i) ? bal : myb;
      tmask |= pred ? (1ull << i) : 0ull;
    }
  }
  maskNT[(size_t)ew * NT2 + n0 + lane] = myb;   // 512B coalesced
  maskT[(size_t)blockIdx.y * N_EDGES + e] = tmask;
}

// ---------------------------------------------------------------------------
// K2m: Mpb[p][e][d] (bf16) partial of (H^T X) + per-chunk popcounts PeCnt.
// 512 blocks = 32 e-tiles(256) x 16 K-chunks, p = bid&15 (XCD L2 locality).
// 512 threads, 8 waves (4x2), wave tile 64x64, launch_bounds(512,4) ->
// 2 blocks/CU. Depth-2 counted-vmcnt, 4 LDS buffers, ONE barrier per step
// (restage target (ks+2)%4 was last read at ks-2, two barriers ago).
// ---------------------------------------------------------------------------
__global__ __launch_bounds__(512, 4) void k2m(const u64* __restrict__ maskT,
                                              const ushort* __restrict__ Xt,
                                              ushort* __restrict__ Mpb,
                                              int* __restrict__ PeCnt) {
  __shared__ __align__(16) char ldsB[4][16384];
  __shared__ __align__(16) char ldsM[4][2048];
  const int t = threadIdx.x, lane = t & 63, w = t >> 6;
  const int wr = w >> 1, wc = w & 1;
  const int bid = blockIdx.x;
  const int p  = bid & 15;
  const int eb = (bid >> 4) * 256;
  const int w0 = p * WPC;
  const int nsteps = min(WPC, NWORDS - w0);
  const int l15 = lane & 15, lh = lane >> 4;

  f32x4 acc[4][4];
#pragma unroll
  for (int m = 0; m < 4; ++m)
#pragma unroll
    for (int n = 0; n < 4; ++n) acc[m][n] = (f32x4){0.f, 0.f, 0.f, 0.f};
  int cnt[4] = {0, 0, 0, 0};

  auto stage = [&](int buf, int ks) {
#pragma unroll
    for (int i = 0; i < 2; ++i) {
      const int flat = i * 512 + t;
      const int d = flat >> 3, sp = flat & 7;
      const int s = sp ^ (d & 7);                 // inverse-swizzled source
      const ushort* src = Xt + (size_t)d * XT_STRIDE + (w0 + ks) * 64 + s * 8;
      GLOAD_LDS16(src, &ldsB[buf][(i * 512 + w * 64) * 16]);
    }
    const char* msrc = (const char*)(maskT + (size_t)(w0 + ks) * N_EDGES + eb) +
                       w * 256 + lane * 4;
    GLOAD_LDS4(msrc, &ldsM[buf][w * 256]);
  };

  stage(0, 0);
  stage(1, 1);
  for (int ks = 0; ks < nsteps; ++ks) {
    const int buf = ks & 3;
    if (ks + 2 < nsteps) stage((ks + 2) & 3, ks + 2);
    const int ahead = min(nsteps - 1 - ks, 2);
    if (ahead == 2)      asm volatile("s_waitcnt vmcnt(6)" ::: "memory");
    else if (ahead == 1) asm volatile("s_waitcnt vmcnt(3)" ::: "memory");
    else                 asm volatile("s_waitcnt vmcnt(0)" ::: "memory");
    __builtin_amdgcn_s_barrier();
    __builtin_amdgcn_sched_barrier(0);

    const u64* mrow = (const u64*)&ldsM[buf][0];
    u64 wd[4];
#pragma unroll
    for (int m = 0; m < 4; ++m) {
      wd[m] = mrow[wr * 64 + m * 16 + l15];
      cnt[m] += __popcll(wd[m]);
    }

#pragma unroll
    for (int kh = 0; kh < 2; ++kh) {
      bf16x8_t bf[4];
#pragma unroll
      for (int fn = 0; fn < 4; ++fn) {
        const int c = wc * 64 + fn * 16 + l15;
        const int s = kh * 4 + lh;
        const int slot = 8 * c + (s ^ (c & 7));   // swizzled read
        bf[fn] = *(const bf16x8_t*)&ldsB[buf][slot * 16];
      }
#pragma unroll
      for (int m = 0; m < 4; ++m) {
        const unsigned int byte = (unsigned int)(wd[m] >> (kh * 32 + lh * 8)) & 0xFFu;
        const bf16x8_t a = expand8(byte);
#pragma unroll
        for (int fn = 0; fn < 4; ++fn)
          acc[m][fn] = mfma16(a, bf[fn], acc[m][fn]);
      }
    }
  }
  FENCED_BARRIER();   // all waves done with last buffer before epilogue reuse

  // epilogue: acc -> bf16 via LDS bounce (4 phases of 64 rows x 128 cols)
  ushort* ush = (ushort*)ldsB;
#pragma unroll
  for (int m = 0; m < 4; ++m) {
#pragma unroll
    for (int fn = 0; fn < 4; ++fn)
#pragma unroll
      for (int r = 0; r < 4; ++r) {
        const int row = wr * 16 + lh * 4 + r;       // 0..63
        const int d = wc * 64 + fn * 16 + l15;
        ush[row * 128 + d] = f2bf(acc[m][fn][r]);
      }
    FENCED_BARRIER();
#pragma unroll
    for (int i = 0; i < 2; ++i) {
      const int task = i * 512 + t;                 // 0..1023 = 64 rows x 16 int4
      const int row = task >> 4, dg = task & 15;
      const int e = eb + (row >> 4) * 64 + m * 16 + (row & 15);
      *(int4*)&Mpb[((size_t)p * N_EDGES + e) * DIM + dg * 8] =
          *(const int4*)&ush[row * 128 + dg * 8];
    }
    FENCED_BARRIER();
  }
  if (lh == 0 && wc == 0) {
#pragma unroll
    for (int m = 0; m < 4; ++m)
      PeCnt[(size_t)p * N_EDGES + eb + wr * 64 + m * 16 + l15] = cnt[m];
  }
}

// ---------------------------------------------------------------------------
// K2rz: M-row = (sum_p Mpb) / De (bf16);  Z = M @ W^T (MFMA);
//       Zt[o][e] = bf16(Z[e][o]). 256 blocks x 32 e. De from PeCnt.
// ---------------------------------------------------------------------------
__global__ __launch_bounds__(256) void k2rz(const ushort* __restrict__ Mpb,
                                            const int* __restrict__ PeCnt,
                                            const float* __restrict__ W,
                                            ushort* __restrict__ Zt) {
  __shared__ __align__(16) ushort Wb[16384];
  __shared__ __align__(16) ushort Mb[5120];    // union: A-tile (4096) / Zl[128][ZPAD]
  const int t = threadIdx.x, lane = t & 63, w = t >> 6;
  const int l15 = lane & 15, lh = lane >> 4;
  const int eb = blockIdx.x * 32;

#pragma unroll
  for (int i = 0; i < 8; ++i) {
    const int task = i * 256 + t;
    const int o = task >> 4, sd = task & 15;
    union { ushort h[8]; int4 v; } u;
    const float* src = W + o * DIM + sd * 8;
#pragma unroll
    for (int j = 0; j < 8; ++j) u.h[j] = f2bf(src[j]);
    *(int4*)&Wb[(o * 16 + (sd ^ (o & 7))) * 8] = u.v;
  }
#pragma unroll
  for (int i = 0; i < 2; ++i) {
    const int task = i * 256 + t;
    const int el = task >> 4, sd = task & 15;
    const int e = eb + el;
    float s[8] = {0.f, 0.f, 0.f, 0.f, 0.f, 0.f, 0.f, 0.f};
    int tot = 0;
#pragma unroll
    for (int p = 0; p < KSPLIT; ++p) {
      union { ushort h[8]; int4 v; } u;
      u.v = *(const int4*)(Mpb + ((size_t)p * N_EDGES + e) * DIM + sd * 8);
#pragma unroll
      for (int j = 0; j < 8; ++j) s[j] += bf2f(u.h[j]);
      tot += PeCnt[(size_t)p * N_EDGES + e];
    }
    const float sc = tot ? (1.0f / (float)tot) : 0.0f;
    union { ushort h[8]; int4 v; } u;
#pragma unroll
    for (int j = 0; j < 8; ++j) u.h[j] = f2bf(s[j] * sc);
    *(int4*)&Mb[(el * 16 + (sd ^ (el & 7))) * 8] = u.v;
  }
  __syncthreads();

  const int ro = w & 1, oc = w >> 1;
  f32x4 acc[4];
#pragma unroll
  for (int fn = 0; fn < 4; ++fn) acc[fn] = (f32x4){0.f, 0.f, 0.f, 0.f};
  const int el = ro * 16 + l15;
#pragma unroll
  for (int ks = 0; ks < 4; ++ks) {
    const bf16x8_t a = *(const bf16x8_t*)&Mb[(el * 16 + ((ks * 4 + lh) ^ (el & 7))) * 8];
#pragma unroll
    for (int fn = 0; fn < 4; ++fn) {
      const int o = oc * 64 + fn * 16 + l15;
      const bf16x8_t bfr = *(const bf16x8_t*)&Wb[(o * 16 + ((ks * 4 + lh) ^ (o & 7))) * 8];
      acc[fn] = mfma16(a, bfr, acc[fn]);
    }
  }
  __syncthreads();

#pragma unroll
  for (int fn = 0; fn < 4; ++fn) {
    const int o = oc * 64 + fn * 16 + l15;
#pragma unroll
    for (int r = 0; r < 4; ++r) {
      const int elc = ro * 16 + lh * 4 + r;
      Mb[o * ZPAD + elc] = f2bf(acc[fn][r]);
    }
  }
  __syncthreads();
#pragma unroll
  for (int i = 0; i < 2; ++i) {
    const int task = i * 256 + t;
    const int o = task >> 2, g = task & 3;
    *(int4*)&Zt[(size_t)o * N_EDGES + eb + g * 8] = *(const int4*)&Mb[o * ZPAD + g * 8];
  }
}

// ---------------------------------------------------------------------------
// K3p: Ypb[p][n][o] (bf16) partial of (H Z) + per-chunk popcounts PnCnt.
// 474 blocks = 79 n-tiles(256) x 6 K-chunks (22x5 + 18 edge-words).
// Same 4-buffer single-barrier pipeline as k2m. 2 blocks/CU.
// Rows >= 20000 compute garbage into pad rows (never read by k3r).
// ---------------------------------------------------------------------------
__global__ __launch_bounds__(512, 4) void k3p(const u64* __restrict__ maskNT,
                                              const ushort* __restrict__ Zt,
                                              ushort* __restrict__ Ypb,
                                              int* __restrict__ PnCnt) {
  __shared__ __align__(16) char ldsB[4][16384];
  __shared__ __align__(16) char ldsM[4][2048];
  const int t = threadIdx.x, lane = t & 63, w = t >> 6;
  const int wr = w >> 1, wc = w & 1;
  const int bid = blockIdx.x;
  const int p  = bid / 79;
  const int nb = (bid % 79) * 256;
  const int kw0 = p * W3PC;
  const int nsteps = min(W3PC, EWORDS - kw0);   // 22,...,18
  const int l15 = lane & 15, lh = lane >> 4;

  f32x4 acc[4][4];
#pragma unroll
  for (int m = 0; m < 4; ++m)
#pragma unroll
    for (int n = 0; n < 4; ++n) acc[m][n] = (f32x4){0.f, 0.f, 0.f, 0.f};
  int cnt[4] = {0, 0, 0, 0};

  auto stage = [&](int buf, int ks) {
#pragma unroll
    for (int i = 0; i < 2; ++i) {
      const int flat = i * 512 + t;
      const int o = flat >> 3, sp = flat & 7;
      const int s = sp ^ (o & 7);
      const ushort* src = Zt + (size_t)o * N_EDGES + (kw0 + ks) * 64 + s * 8;
      GLOAD_LDS16(src, &ldsB[buf][(i * 512 + w * 64) * 16]);
    }
    const char* msrc = (const char*)(maskNT + (size_t)(kw0 + ks) * NT2 + nb) +
                       w * 256 + lane * 4;
    GLOAD_LDS4(msrc, &ldsM[buf][w * 256]);
  };

  stage(0, 0);
  stage(1, 1);
  for (int ks = 0; ks < nsteps; ++ks) {
    const int buf = ks & 3;
    if (ks + 2 < nsteps) stage((ks + 2) & 3, ks + 2);
    const int ahead = min(nsteps - 1 - ks, 2);
    if (ahead == 2)      asm volatile("s_waitcnt vmcnt(6)" ::: "memory");
    else if (ahead == 1) asm volatile("s_waitcnt vmcnt(3)" ::: "memory");
    else                 asm volatile("s_waitcnt vmcnt(0)" ::: "memory");
    __builtin_amdgcn_s_barrier();
    __builtin_amdgcn_sched_barrier(0);

    const u64* mrow = (const u64*)&ldsM[buf][0];
    u64 wd[4];
#pragma unroll
    for (int m = 0; m < 4; ++m) {
      wd[m] = mrow[wr * 64 + m * 16 + l15];
      cnt[m] += __popcll(wd[m]);
    }

#pragma unroll
    for (int kh = 0; kh < 2; ++kh) {
      bf16x8_t bf[4];
#pragma unroll
      for (int fn = 0; fn < 4; ++fn) {
        const int c = wc * 64 + fn * 16 + l15;
        const int s = kh * 4 + lh;
        const int slot = 8 * c + (s ^ (c & 7));
        bf[fn] = *(const bf16x8_t*)&ldsB[buf][slot * 16];
      }
#pragma unroll
      for (int m = 0; m < 4; ++m) {
        const unsigned int byte = (unsigned int)(wd[m] >> (kh * 32 + lh * 8)) & 0xFFu;
        const bf16x8_t a = expand8(byte);
#pragma unroll
        for (int fn = 0; fn < 4; ++fn)
          acc[m][fn] = mfma16(a, bf[fn], acc[m][fn]);
      }
    }
  }
  FENCED_BARRIER();

  // epilogue: acc -> bf16 via LDS bounce (4 phases of 64 rows x 128 cols)
  ushort* ush = (ushort*)ldsB;
#pragma unroll
  for (int m = 0; m < 4; ++m) {
#pragma unroll
    for (int fn = 0; fn < 4; ++fn)
#pragma unroll
      for (int r = 0; r < 4; ++r) {
        const int row = wr * 16 + lh * 4 + r;
        const int d = wc * 64 + fn * 16 + l15;
        ush[row * 128 + d] = f2bf(acc[m][fn][r]);
      }
    FENCED_BARRIER();
#pragma unroll
    for (int i = 0; i < 2; ++i) {
      const int task = i * 512 + t;
      const int row = task >> 4, dg = task & 15;
      const int n = nb + (row >> 4) * 64 + m * 16 + (row & 15);   // < 20224
      *(int4*)&Ypb[((size_t)p * YP_ROWS + n) * DIM + dg * 8] =
          *(const int4*)&ush[row * 128 + dg * 8];
    }
    FENCED_BARRIER();
  }
  if (lh == 0 && wc == 0) {
#pragma unroll
    for (int m = 0; m < 4; ++m)
      PnCnt[(size_t)p * YP_ROWS + nb + wr * 64 + m * 16 + l15] = cnt[m];
  }
}

// ---------------------------------------------------------------------------
// K3r: out[n][o] = (sum_p Ypb[p][n][o]) / Dv[n] + b[o]. 1250 blocks exact.
// ---------------------------------------------------------------------------
__global__ __launch_bounds__(256) void k3r(const ushort* __restrict__ Ypb,
                                           const int* __restrict__ PnCnt,
                                           const float* __restrict__ bias,
                                           float* __restrict__ out) {
  const int task = blockIdx.x * 256 + threadIdx.x;   // < 320000
  const int n = task >> 4;
  const int o0 = (task & 15) * 8;
  float s[8] = {0.f, 0.f, 0.f, 0.f, 0.f, 0.f, 0.f, 0.f};
  int tot = 0;
#pragma unroll
  for (int p = 0; p < K3SPLIT; ++p) {
    union { ushort h[8]; int4 v; } u;
    u.v = *(const int4*)(Ypb + ((size_t)p * YP_ROWS + n) * DIM + o0);
#pragma unroll
    for (int j = 0; j < 8; ++j) s[j] += bf2f(u.h[j]);
    tot += PnCnt[(size_t)p * YP_ROWS + n];
  }
  const float dv = tot ? (1.0f / (float)tot) : 0.0f;
  float4 r0, r1;
  const float4 b0 = *(const float4*)(bias + o0);
  const float4 b1 = *(const float4*)(bias + o0 + 4);
  r0.x = s[0] * dv + b0.x; r0.y = s[1] * dv + b0.y;
  r0.z = s[2] * dv + b0.z; r0.w = s[3] * dv + b0.w;
  r1.x = s[4] * dv + b1.x; r1.y = s[5] * dv + b1.y;
  r1.z = s[6] * dv + b1.z; r1.w = s[7] * dv + b1.w;
  float4* dst = (float4*)(out + (size_t)n * DIM + o0);
  dst[0] = r0; dst[1] = r1;
}

// ---------------------------------------------------------------------------
extern "C" void kernel_launch(void* const* d_in, const int* in_sizes, int n_in,
                              void* d_out, int out_size, void* d_ws, size_t ws_size,
                              hipStream_t stream) {
  const float* X = (const float*)d_in[0];
  const float* H = (const float*)d_in[1];
  const float* W = (const float*)d_in[2];
  const float* b = (const float*)d_in[3];
  float* out = (float*)d_out;

  char* ws = (char*)d_ws;
  u64*    maskT  = (u64*)(ws + 0);             // 313*8192*8     = 20,512,768
  u64*    maskNT = (u64*)(ws + 20512768);      // 128*20224*8    = 20,709,376
  ushort* Xt     = (ushort*)(ws + 41222144);   // 128*20032*2    =  5,128,192
  ushort* Mpb    = (ushort*)(ws + 46350336);   // 16*8192*128*2  = 33,554,432
  ushort* Zt     = (ushort*)(ws + 79904768);   // 128*8192*2     =  2,097,152
  ushort* Ypb    = (ushort*)(ws + 82001920);   // 6*20224*128*2  = 31,064,064
  int*    PeCnt  = (int*)(ws + 113065984);     // 16*8192*4      =    524,288
  int*    PnCnt  = (int*)(ws + 113590272);     // 6*20224*4      =    485,376

  k0_xt  <<<313, 256, 0, stream>>>(X, Xt);
  k1_mask<<<dim3(32, 313), 256, 0, stream>>>(H, maskNT, maskT);
  k2m    <<<512, 512, 0, stream>>>(maskT, Xt, Mpb, PeCnt);
  k2rz   <<<256, 256, 0, stream>>>(Mpb, PeCnt, W, Zt);
  k3p    <<<474, 512, 0, stream>>>(maskNT, Zt, Ypb, PnCnt);
  k3r    <<<1250, 256, 0, stream>>>(Ypb, PnCnt, b, out);
}

// Round 13
// 276.574 us; speedup vs baseline: 1.8673x; 1.0065x over previous
//
#include <hip/hip_runtime.h>

#define N_NODES 20000
#define N_EDGES 8192
#define DIM 128
#define NWORDS 313        // ceil(20000/64) node-words (K-dim of k2m)
#define EWORDS 128        // 8192/64 edge-words (K-dim of k3p)
#define XT_STRIDE 20032   // NWORDS*64, padded node dim for Xt
#define NT2 20224         // maskNT row stride (79*256); cols >=20032 unwritten garbage
#define YP_ROWS 20224     // Yp row capacity (79*256)
#define KSPLIT 16         // K-chunks in k2m: 15x20 + 13 node-words
#define WPC 20
#define ZPAD 40           // Zl row stride (ushort) in k2rz bounce
#define K3SPLIT 6         // K-chunks in k3p: 5x22 + 18 edge-words
#define W3PC 22

typedef unsigned long long u64;
typedef __attribute__((ext_vector_type(8))) __bf16 bf16x8_t;
typedef __attribute__((ext_vector_type(4))) float f32x4;

__device__ __forceinline__ f32x4 mfma16(bf16x8_t a, bf16x8_t b, f32x4 c) {
  return __builtin_amdgcn_mfma_f32_16x16x32_bf16(a, b, c, 0, 0, 0);
}

__device__ __forceinline__ ushort f2bf(float f) {
  unsigned int x = __float_as_uint(f);
  unsigned int r = (x + 0x7FFFu + ((x >> 16) & 1u)) >> 16;
  return (ushort)r;
}
__device__ __forceinline__ float bf2f(ushort h) {
  return __uint_as_float(((unsigned int)h) << 16);
}

__device__ __forceinline__ bf16x8_t expand8(unsigned int byte) {
  union { unsigned int u[4]; bf16x8_t v; } A;
  const unsigned int w = byte | (byte << 15);
#pragma unroll
  for (int p = 0; p < 4; ++p) {
    A.u[p] = ((w >> (2 * p)) & 0x00010001u) * 0x3F80u;
  }
  return A.v;
}

#define GLOAD_LDS16(g, l)                                                  \
  __builtin_amdgcn_global_load_lds(                                        \
      (const __attribute__((address_space(1))) void*)(g),                  \
      (__attribute__((address_space(3))) void*)(l), 16, 0, 0)
#define GLOAD_LDS4(g, l)                                                   \
  __builtin_amdgcn_global_load_lds(                                        \
      (const __attribute__((address_space(1))) void*)(g),                  \
      (__attribute__((address_space(3))) void*)(l), 4, 0, 0)

#define FENCED_BARRIER()                          \
  do {                                            \
    asm volatile("" ::: "memory");                \
    __builtin_amdgcn_s_barrier();                 \
    asm volatile("" ::: "memory");                \
  } while (0)

// ---------------------------------------------------------------------------
// K0: Xt[d][n] = bf16(X[n][d]), n padded to XT_STRIDE with zeros.
// ---------------------------------------------------------------------------
__global__ __launch_bounds__(256) void k0_xt(const float* __restrict__ X,
                                             ushort* __restrict__ Xt) {
  __shared__ float T[64][129];
  const int t = threadIdx.x;
  const int n0 = blockIdx.x * 64;
#pragma unroll
  for (int i = 0; i < 32; ++i) {
    const int flat = i * 256 + t;
    const int nl = flat >> 7, d = flat & 127;
    const int n = n0 + nl;
    T[nl][d] = (n < N_NODES) ? X[(size_t)n * DIM + d] : 0.f;
  }
  __syncthreads();
  const int d = t >> 1, half = t & 1;
#pragma unroll
  for (int g = 0; g < 4; ++g) {
    union { ushort h[8]; int4 v; } u;
#pragma unroll
    for (int j = 0; j < 8; ++j) {
      const int nl = half * 32 + g * 8 + j;
      u.h[j] = f2bf(T[nl][d]);
    }
    *(int4*)&Xt[(size_t)d * XT_STRIDE + n0 + half * 32 + g * 8] = u.v;
  }
}

// ---------------------------------------------------------------------------
// K1: stream H once -> maskT[c][e], maskNT[ew][n]. Clean/guarded loop split.
// ---------------------------------------------------------------------------
__global__ __launch_bounds__(256) void k1_mask(const float* __restrict__ H,
                                               u64* __restrict__ maskNT,
                                               u64* __restrict__ maskT) {
  const int tid  = threadIdx.x;
  const int wave = tid >> 6, lane = tid & 63;
  const int e  = blockIdx.x * 256 + wave * 64 + lane;
  const int n0 = blockIdx.y * 64;
  const int ew = blockIdx.x * 4 + wave;   // edge-window index 0..127

  u64 tmask = 0, myb = 0;
  if (n0 + 63 < N_NODES) {
#pragma unroll 8
    for (int i = 0; i < 64; ++i) {
      const bool pred = (H[(size_t)(n0 + i) * N_EDGES + e] != 0.0f);
      const u64 bal = __ballot(pred);
      myb = (lane == i) ? bal : myb;
      tmask |= pred ? (1ull << i) : 0ull;
    }
  } else {
#pragma unroll 8
    for (int i = 0; i < 64; ++i) {
      const int n = n0 + i;
      const bool pred = (n < N_NODES) && (H[(size_t)n * N_EDGES + e] != 0.0f);
      const u64 bal = __ballot(pred);
      myb = (lane == i) ? bal : myb;
      tmask |= pred ? (1ull << i) : 0ull;
    }
  }
  maskNT[(size_t)ew * NT2 + n0 + lane] = myb;   // 512B coalesced
  maskT[(size_t)blockIdx.y * N_EDGES + e] = tmask;
}

// ---------------------------------------------------------------------------
// K2m: Mpb[p][e][d] (bf16) partial of (H^T X) + per-chunk popcounts PeCnt.
// 512 blocks = 32 e-tiles(256) x 16 K-chunks, p = bid&15 (XCD L2 locality).
// 512 threads, 8 waves (4x2), wave tile 64x64, launch_bounds(512,4) ->
// 2 blocks/CU. Depth-2 counted-vmcnt, 4 LDS buffers, ONE barrier per step.
// T5: s_setprio(1) around the MFMA cluster.
// ---------------------------------------------------------------------------
__global__ __launch_bounds__(512, 4) void k2m(const u64* __restrict__ maskT,
                                              const ushort* __restrict__ Xt,
                                              ushort* __restrict__ Mpb,
                                              int* __restrict__ PeCnt) {
  __shared__ __align__(16) char ldsB[4][16384];
  __shared__ __align__(16) char ldsM[4][2048];
  const int t = threadIdx.x, lane = t & 63, w = t >> 6;
  const int wr = w >> 1, wc = w & 1;
  const int bid = blockIdx.x;
  const int p  = bid & 15;
  const int eb = (bid >> 4) * 256;
  const int w0 = p * WPC;
  const int nsteps = min(WPC, NWORDS - w0);
  const int l15 = lane & 15, lh = lane >> 4;

  f32x4 acc[4][4];
#pragma unroll
  for (int m = 0; m < 4; ++m)
#pragma unroll
    for (int n = 0; n < 4; ++n) acc[m][n] = (f32x4){0.f, 0.f, 0.f, 0.f};
  int cnt[4] = {0, 0, 0, 0};

  auto stage = [&](int buf, int ks) {
#pragma unroll
    for (int i = 0; i < 2; ++i) {
      const int flat = i * 512 + t;
      const int d = flat >> 3, sp = flat & 7;
      const int s = sp ^ (d & 7);                 // inverse-swizzled source
      const ushort* src = Xt + (size_t)d * XT_STRIDE + (w0 + ks) * 64 + s * 8;
      GLOAD_LDS16(src, &ldsB[buf][(i * 512 + w * 64) * 16]);
    }
    const char* msrc = (const char*)(maskT + (size_t)(w0 + ks) * N_EDGES + eb) +
                       w * 256 + lane * 4;
    GLOAD_LDS4(msrc, &ldsM[buf][w * 256]);
  };

  stage(0, 0);
  stage(1, 1);
  for (int ks = 0; ks < nsteps; ++ks) {
    const int buf = ks & 3;
    if (ks + 2 < nsteps) stage((ks + 2) & 3, ks + 2);
    const int ahead = min(nsteps - 1 - ks, 2);
    if (ahead == 2)      asm volatile("s_waitcnt vmcnt(6)" ::: "memory");
    else if (ahead == 1) asm volatile("s_waitcnt vmcnt(3)" ::: "memory");
    else                 asm volatile("s_waitcnt vmcnt(0)" ::: "memory");
    __builtin_amdgcn_s_barrier();
    __builtin_amdgcn_sched_barrier(0);

    const u64* mrow = (const u64*)&ldsM[buf][0];
    u64 wd[4];
#pragma unroll
    for (int m = 0; m < 4; ++m) {
      wd[m] = mrow[wr * 64 + m * 16 + l15];
      cnt[m] += __popcll(wd[m]);
    }

    __builtin_amdgcn_s_setprio(1);
#pragma unroll
    for (int kh = 0; kh < 2; ++kh) {
      bf16x8_t bf[4];
#pragma unroll
      for (int fn = 0; fn < 4; ++fn) {
        const int c = wc * 64 + fn * 16 + l15;
        const int s = kh * 4 + lh;
        const int slot = 8 * c + (s ^ (c & 7));   // swizzled read
        bf[fn] = *(const bf16x8_t*)&ldsB[buf][slot * 16];
      }
#pragma unroll
      for (int m = 0; m < 4; ++m) {
        const unsigned int byte = (unsigned int)(wd[m] >> (kh * 32 + lh * 8)) & 0xFFu;
        const bf16x8_t a = expand8(byte);
#pragma unroll
        for (int fn = 0; fn < 4; ++fn)
          acc[m][fn] = mfma16(a, bf[fn], acc[m][fn]);
      }
    }
    __builtin_amdgcn_s_setprio(0);
  }
  FENCED_BARRIER();   // all waves done with last buffer before epilogue reuse

  // epilogue: acc -> bf16 via LDS bounce (4 phases of 64 rows x 128 cols)
  ushort* ush = (ushort*)ldsB;
#pragma unroll
  for (int m = 0; m < 4; ++m) {
#pragma unroll
    for (int fn = 0; fn < 4; ++fn)
#pragma unroll
      for (int r = 0; r < 4; ++r) {
        const int row = wr * 16 + lh * 4 + r;       // 0..63
        const int d = wc * 64 + fn * 16 + l15;
        ush[row * 128 + d] = f2bf(acc[m][fn][r]);
      }
    FENCED_BARRIER();
#pragma unroll
    for (int i = 0; i < 2; ++i) {
      const int task = i * 512 + t;                 // 0..1023 = 64 rows x 16 int4
      const int row = task >> 4, dg = task & 15;
      const int e = eb + (row >> 4) * 64 + m * 16 + (row & 15);
      *(int4*)&Mpb[((size_t)p * N_EDGES + e) * DIM + dg * 8] =
          *(const int4*)&ush[row * 128 + dg * 8];
    }
    FENCED_BARRIER();
  }
  if (lh == 0 && wc == 0) {
#pragma unroll
    for (int m = 0; m < 4; ++m)
      PeCnt[(size_t)p * N_EDGES + eb + wr * 64 + m * 16 + l15] = cnt[m];
  }
}

// ---------------------------------------------------------------------------
// K2rz: M-row = (sum_p Mpb) / De (bf16);  Z = M @ W^T (MFMA);
//       Zt[o][e] = bf16(Z[e][o]). 256 blocks x 32 e. De from PeCnt.
// ---------------------------------------------------------------------------
__global__ __launch_bounds__(256) void k2rz(const ushort* __restrict__ Mpb,
                                            const int* __restrict__ PeCnt,
                                            const float* __restrict__ W,
                                            ushort* __restrict__ Zt) {
  __shared__ __align__(16) ushort Wb[16384];
  __shared__ __align__(16) ushort Mb[5120];    // union: A-tile (4096) / Zl[128][ZPAD]
  const int t = threadIdx.x, lane = t & 63, w = t >> 6;
  const int l15 = lane & 15, lh = lane >> 4;
  const int eb = blockIdx.x * 32;

#pragma unroll
  for (int i = 0; i < 8; ++i) {
    const int task = i * 256 + t;
    const int o = task >> 4, sd = task & 15;
    union { ushort h[8]; int4 v; } u;
    const float* src = W + o * DIM + sd * 8;
#pragma unroll
    for (int j = 0; j < 8; ++j) u.h[j] = f2bf(src[j]);
    *(int4*)&Wb[(o * 16 + (sd ^ (o & 7))) * 8] = u.v;
  }
#pragma unroll
  for (int i = 0; i < 2; ++i) {
    const int task = i * 256 + t;
    const int el = task >> 4, sd = task & 15;
    const int e = eb + el;
    float s[8] = {0.f, 0.f, 0.f, 0.f, 0.f, 0.f, 0.f, 0.f};
    int tot = 0;
#pragma unroll
    for (int p = 0; p < KSPLIT; ++p) {
      union { ushort h[8]; int4 v; } u;
      u.v = *(const int4*)(Mpb + ((size_t)p * N_EDGES + e) * DIM + sd * 8);
#pragma unroll
      for (int j = 0; j < 8; ++j) s[j] += bf2f(u.h[j]);
      tot += PeCnt[(size_t)p * N_EDGES + e];
    }
    const float sc = tot ? (1.0f / (float)tot) : 0.0f;
    union { ushort h[8]; int4 v; } u;
#pragma unroll
    for (int j = 0; j < 8; ++j) u.h[j] = f2bf(s[j] * sc);
    *(int4*)&Mb[(el * 16 + (sd ^ (el & 7))) * 8] = u.v;
  }
  __syncthreads();

  const int ro = w & 1, oc = w >> 1;
  f32x4 acc[4];
#pragma unroll
  for (int fn = 0; fn < 4; ++fn) acc[fn] = (f32x4){0.f, 0.f, 0.f, 0.f};
  const int el = ro * 16 + l15;
#pragma unroll
  for (int ks = 0; ks < 4; ++ks) {
    const bf16x8_t a = *(const bf16x8_t*)&Mb[(el * 16 + ((ks * 4 + lh) ^ (el & 7))) * 8];
#pragma unroll
    for (int fn = 0; fn < 4; ++fn) {
      const int o = oc * 64 + fn * 16 + l15;
      const bf16x8_t bfr = *(const bf16x8_t*)&Wb[(o * 16 + ((ks * 4 + lh) ^ (o & 7))) * 8];
      acc[fn] = mfma16(a, bfr, acc[fn]);
    }
  }
  __syncthreads();

#pragma unroll
  for (int fn = 0; fn < 4; ++fn) {
    const int o = oc * 64 + fn * 16 + l15;
#pragma unroll
    for (int r = 0; r < 4; ++r) {
      const int elc = ro * 16 + lh * 4 + r;
      Mb[o * ZPAD + elc] = f2bf(acc[fn][r]);
    }
  }
  __syncthreads();
#pragma unroll
  for (int i = 0; i < 2; ++i) {
    const int task = i * 256 + t;
    const int o = task >> 2, g = task & 3;
    *(int4*)&Zt[(size_t)o * N_EDGES + eb + g * 8] = *(const int4*)&Mb[o * ZPAD + g * 8];
  }
}

// ---------------------------------------------------------------------------
// K3p: Ypb[p][n][o] (bf16) partial of (H Z) + per-chunk popcounts PnCnt.
// 474 blocks = 79 n-tiles(256) x 6 K-chunks (22x5 + 18 edge-words).
// Same 4-buffer single-barrier pipeline as k2m, T5 setprio. 2 blocks/CU.
// ---------------------------------------------------------------------------
__global__ __launch_bounds__(512, 4) void k3p(const u64* __restrict__ maskNT,
                                              const ushort* __restrict__ Zt,
                                              ushort* __restrict__ Ypb,
                                              int* __restrict__ PnCnt) {
  __shared__ __align__(16) char ldsB[4][16384];
  __shared__ __align__(16) char ldsM[4][2048];
  const int t = threadIdx.x, lane = t & 63, w = t >> 6;
  const int wr = w >> 1, wc = w & 1;
  const int bid = blockIdx.x;
  const int p  = bid / 79;
  const int nb = (bid % 79) * 256;
  const int kw0 = p * W3PC;
  const int nsteps = min(W3PC, EWORDS - kw0);   // 22,...,18
  const int l15 = lane & 15, lh = lane >> 4;

  f32x4 acc[4][4];
#pragma unroll
  for (int m = 0; m < 4; ++m)
#pragma unroll
    for (int n = 0; n < 4; ++n) acc[m][n] = (f32x4){0.f, 0.f, 0.f, 0.f};
  int cnt[4] = {0, 0, 0, 0};

  auto stage = [&](int buf, int ks) {
#pragma unroll
    for (int i = 0; i < 2; ++i) {
      const int flat = i * 512 + t;
      const int o = flat >> 3, sp = flat & 7;
      const int s = sp ^ (o & 7);
      const ushort* src = Zt + (size_t)o * N_EDGES + (kw0 + ks) * 64 + s * 8;
      GLOAD_LDS16(src, &ldsB[buf][(i * 512 + w * 64) * 16]);
    }
    const char* msrc = (const char*)(maskNT + (size_t)(kw0 + ks) * NT2 + nb) +
                       w * 256 + lane * 4;
    GLOAD_LDS4(msrc, &ldsM[buf][w * 256]);
  };

  stage(0, 0);
  stage(1, 1);
  for (int ks = 0; ks < nsteps; ++ks) {
    const int buf = ks & 3;
    if (ks + 2 < nsteps) stage((ks + 2) & 3, ks + 2);
    const int ahead = min(nsteps - 1 - ks, 2);
    if (ahead == 2)      asm volatile("s_waitcnt vmcnt(6)" ::: "memory");
    else if (ahead == 1) asm volatile("s_waitcnt vmcnt(3)" ::: "memory");
    else                 asm volatile("s_waitcnt vmcnt(0)" ::: "memory");
    __builtin_amdgcn_s_barrier();
    __builtin_amdgcn_sched_barrier(0);

    const u64* mrow = (const u64*)&ldsM[buf][0];
    u64 wd[4];
#pragma unroll
    for (int m = 0; m < 4; ++m) {
      wd[m] = mrow[wr * 64 + m * 16 + l15];
      cnt[m] += __popcll(wd[m]);
    }

    __builtin_amdgcn_s_setprio(1);
#pragma unroll
    for (int kh = 0; kh < 2; ++kh) {
      bf16x8_t bf[4];
#pragma unroll
      for (int fn = 0; fn < 4; ++fn) {
        const int c = wc * 64 + fn * 16 + l15;
        const int s = kh * 4 + lh;
        const int slot = 8 * c + (s ^ (c & 7));
        bf[fn] = *(const bf16x8_t*)&ldsB[buf][slot * 16];
      }
#pragma unroll
      for (int m = 0; m < 4; ++m) {
        const unsigned int byte = (unsigned int)(wd[m] >> (kh * 32 + lh * 8)) & 0xFFu;
        const bf16x8_t a = expand8(byte);
#pragma unroll
        for (int fn = 0; fn < 4; ++fn)
          acc[m][fn] = mfma16(a, bf[fn], acc[m][fn]);
      }
    }
    __builtin_amdgcn_s_setprio(0);
  }
  FENCED_BARRIER();

  // epilogue: acc -> bf16 via LDS bounce (4 phases of 64 rows x 128 cols)
  ushort* ush = (ushort*)ldsB;
#pragma unroll
  for (int m = 0; m < 4; ++m) {
#pragma unroll
    for (int fn = 0; fn < 4; ++fn)
#pragma unroll
      for (int r = 0; r < 4; ++r) {
        const int row = wr * 16 + lh * 4 + r;
        const int d = wc * 64 + fn * 16 + l15;
        ush[row * 128 + d] = f2bf(acc[m][fn][r]);
      }
    FENCED_BARRIER();
#pragma unroll
    for (int i = 0; i < 2; ++i) {
      const int task = i * 512 + t;
      const int row = task >> 4, dg = task & 15;
      const int n = nb + (row >> 4) * 64 + m * 16 + (row & 15);   // < 20224
      *(int4*)&Ypb[((size_t)p * YP_ROWS + n) * DIM + dg * 8] =
          *(const int4*)&ush[row * 128 + dg * 8];
    }
    FENCED_BARRIER();
  }
  if (lh == 0 && wc == 0) {
#pragma unroll
    for (int m = 0; m < 4; ++m)
      PnCnt[(size_t)p * YP_ROWS + nb + wr * 64 + m * 16 + l15] = cnt[m];
  }
}

// ---------------------------------------------------------------------------
// K3r: out[n][o] = (sum_p Ypb[p][n][o]) / Dv[n] + b[o]. 1250 blocks exact.
// ---------------------------------------------------------------------------
__global__ __launch_bounds__(256) void k3r(const ushort* __restrict__ Ypb,
                                           const int* __restrict__ PnCnt,
                                           const float* __restrict__ bias,
                                           float* __restrict__ out) {
  const int task = blockIdx.x * 256 + threadIdx.x;   // < 320000
  const int n = task >> 4;
  const int o0 = (task & 15) * 8;
  float s[8] = {0.f, 0.f, 0.f, 0.f, 0.f, 0.f, 0.f, 0.f};
  int tot = 0;
#pragma unroll
  for (int p = 0; p < K3SPLIT; ++p) {
    union { ushort h[8]; int4 v; } u;
    u.v = *(const int4*)(Ypb + ((size_t)p * YP_ROWS + n) * DIM + o0);
#pragma unroll
    for (int j = 0; j < 8; ++j) s[j] += bf2f(u.h[j]);
    tot += PnCnt[(size_t)p * YP_ROWS + n];
  }
  const float dv = tot ? (1.0f / (float)tot) : 0.0f;
  float4 r0, r1;
  const float4 b0 = *(const float4*)(bias + o0);
  const float4 b1 = *(const float4*)(bias + o0 + 4);
  r0.x = s[0] * dv + b0.x; r0.y = s[1] * dv + b0.y;
  r0.z = s[2] * dv + b0.z; r0.w = s[3] * dv + b0.w;
  r1.x = s[4] * dv + b1.x; r1.y = s[5] * dv + b1.y;
  r1.z = s[6] * dv + b1.z; r1.w = s[7] * dv + b1.w;
  float4* dst = (float4*)(out + (size_t)n * DIM + o0);
  dst[0] = r0; dst[1] = r1;
}

// ---------------------------------------------------------------------------
extern "C" void kernel_launch(void* const* d_in, const int* in_sizes, int n_in,
                              void* d_out, int out_size, void* d_ws, size_t ws_size,
                              hipStream_t stream) {
  const float* X = (const float*)d_in[0];
  const float* H = (const float*)d_in[1];
  const float* W = (const float*)d_in[2];
  const float* b = (const float*)d_in[3];
  float* out = (float*)d_out;

  char* ws = (char*)d_ws;
  u64*    maskT  = (u64*)(ws + 0);             // 313*8192*8     = 20,512,768
  u64*    maskNT = (u64*)(ws + 20512768);      // 128*20224*8    = 20,709,376
  ushort* Xt     = (ushort*)(ws + 41222144);   // 128*20032*2    =  5,128,192
  ushort* Mpb    = (ushort*)(ws + 46350336);   // 16*8192*128*2  = 33,554,432
  ushort* Zt     = (ushort*)(ws + 79904768);   // 128*8192*2     =  2,097,152
  ushort* Ypb    = (ushort*)(ws + 82001920);   // 6*20224*128*2  = 31,064,064
  int*    PeCnt  = (int*)(ws + 113065984);     // 16*8192*4      =    524,288
  int*    PnCnt  = (int*)(ws + 113590272);     // 6*20224*4      =    485,376

  k0_xt  <<<313, 256, 0, stream>>>(X, Xt);
  k1_mask<<<dim3(32, 313), 256, 0, stream>>>(H, maskNT, maskT);
  k2m    <<<512, 512, 0, stream>>>(maskT, Xt, Mpb, PeCnt);
  k2rz   <<<256, 256, 0, stream>>>(Mpb, PeCnt, W, Zt);
  k3p    <<<474, 512, 0, stream>>>(maskNT, Zt, Ypb, PnCnt);
  k3r    <<<1250, 256, 0, stream>>>(Ypb, PnCnt, b, out);
}